// Round 11
// baseline (201.886 us; speedup 1.0000x reference)
//
#include <hip/hip_runtime.h>
#include <hip/hip_bf16.h>
#include <math.h>

#define LSEQ 4096
#define NR   16384   // B*L
#define NB   4
#define CHUNK 32
#define NCH  128

typedef short bf16x8 __attribute__((ext_vector_type(8)));
typedef float f32x4  __attribute__((ext_vector_type(4)));
typedef float f32x2  __attribute__((ext_vector_type(2)));

typedef __attribute__((address_space(1))) const void gvoid_t;
typedef __attribute__((address_space(3))) void svoid_t;

__device__ __forceinline__ void gld_lds16(void* lds, const void* g) {
    __builtin_amdgcn_global_load_lds((gvoid_t*)g, (svoid_t*)lds, 16, 0, 0);
}

__device__ __forceinline__ unsigned short to_bf16(float f) {
    union { float f; unsigned u; } x; x.f = f;
    unsigned r = (x.u + 0x7fff + ((x.u >> 16) & 1)) >> 16;
    return (unsigned short)r;
}
__device__ __forceinline__ float bf2f(unsigned short u) {
    union { unsigned u; float f; } x; x.u = ((unsigned)u) << 16;
    return x.f;
}
__device__ __forceinline__ float softplus_f(float x) {
    return x > 20.f ? x : __logf(1.f + __expf(x));
}
__device__ __forceinline__ float silu_f(float x) {
    return x / (1.f + __expf(-x));
}

// packed pow chain: a2[i] = {r^(2i+1), r^(2i+2)} — bit-identical mult trees to scalar version
__device__ __forceinline__ void pow_chain16_pk(float r, f32x2* a2) {
    float r2 = r * r;
    float r4 = r2 * r2;
    float r8 = r4 * r4;
    f32x2 v01 = { r, r2 };
    a2[0] = v01;
    a2[1] = v01 * r2;    // r3,  r4
    a2[2] = v01 * r4;    // r5,  r6
    a2[3] = a2[1] * r4;  // r7,  r8
    a2[4] = v01 * r8;    // r9,  r10
    a2[5] = a2[1] * r8;  // r11, r12
    a2[6] = a2[2] * r8;  // r13, r14
    a2[7] = a2[3] * r8;  // r15, r16
}

// per-thread check: An[n] == (n+1) * An[0] for all n (power-structure of A)
__device__ __forceinline__ bool pow_ok16(const float* An) {
    bool ok = true;
    #pragma unroll
    for (int n = 1; n < 16; ++n) {
        float ref = (float)(n + 1) * An[0];
        ok = ok && (fabsf(An[n] - ref) <= 1e-4f * fabsf(An[n]) + 1e-30f);
    }
    return ok;
}

// ---------------- K1: merged front (ln | wct | wxpt | aneg | Wt-transpose) ----------------
__global__ __launch_bounds__(256) void front_kernel(const float* __restrict__ in1,
                                                    const float* __restrict__ in2,
                                                    const float* __restrict__ g,
                                                    const float* __restrict__ beta,
                                                    const float* __restrict__ Wm,
                                                    const float* __restrict__ Wo,
                                                    const float* __restrict__ Wxp,
                                                    const float* __restrict__ A_log,
                                                    const float* __restrict__ W,
                                                    unsigned short* __restrict__ Abf,
                                                    unsigned short* __restrict__ WcT,
                                                    unsigned short* __restrict__ Wxpt,
                                                    float* __restrict__ anegp,
                                                    unsigned short* __restrict__ Wt) {
    __shared__ float tile[256][33];   // 8448 floats; transpose branch uses flat 64*65=4160
    int blk = blockIdx.x;
    int tid = threadIdx.x;
    if (blk < 512) {
        // ---- layernorm + transpose + bf16 ----
        __shared__ float s1[8][32], s2[8][32];
        __shared__ float smu[32], srs[32];
        int b  = blk >> 7;
        int t0 = (blk & 127) * 32;
        #pragma unroll
        for (int p = 0; p < 8; ++p) {
            int c = p * 32 + (tid >> 3);
            int toff = (tid & 7) * 4;
            const float* src = (c < 128) ? &in1[((size_t)(b * 128 + c)) * LSEQ + t0 + toff]
                                         : &in2[((size_t)(b * 128 + (c - 128))) * LSEQ + t0 + toff];
            float4 v = *(const float4*)src;
            tile[c][toff] = v.x; tile[c][toff+1] = v.y;
            tile[c][toff+2] = v.z; tile[c][toff+3] = v.w;
        }
        __syncthreads();
        {
            int t = tid & 31, gg = tid >> 5;
            float a1 = 0.f, a2 = 0.f;
            #pragma unroll
            for (int i = 0; i < 32; ++i) {
                float v = tile[gg * 32 + i][t];
                a1 += v; a2 += v * v;
            }
            s1[gg][t] = a1; s2[gg][t] = a2;
        }
        __syncthreads();
        if (tid < 32) {
            float a1 = 0.f, a2 = 0.f;
            #pragma unroll
            for (int gg = 0; gg < 8; ++gg) { a1 += s1[gg][tid]; a2 += s2[gg][tid]; }
            float m = a1 * (1.f / 256.f);
            float var = a2 * (1.f / 256.f) - m * m;
            smu[tid] = m;
            srs[tid] = rsqrtf(var + 1e-5f);
        }
        __syncthreads();
        int c = tid;
        float gc = g[c], bc = beta[c];
        #pragma unroll 4
        for (int t = 0; t < 32; ++t) {
            float v = (tile[c][t] - smu[t]) * srs[t] * gc + bc;
            Abf[((size_t)((b << 12) + t0 + t)) * 256 + c] = to_bf16(v);
        }
    } else if (blk < 768) {
        int gid = (blk - 512) * 256 + tid;    // 65536
        int row = gid >> 7, col = gid & 127;
        float acc = 0.f;
        #pragma unroll 8
        for (int k = 0; k < 256; ++k) acc += Wm[row * 256 + k] * Wo[k * 128 + col];
        WcT[(size_t)col * 512 + row] = to_bf16(acc);
    } else if (blk < 864) {
        int gid = (blk - 768) * 256 + tid;    // 24576
        int n = gid >> 9, k = gid & 511;
        Wxpt[gid] = to_bf16(Wxp[(size_t)k * 48 + n]);
    } else if (blk < 896) {
        int gid = (blk - 864) * 256 + tid;    // 8192
        anegp[gid] = -__expf(A_log[gid]);
    } else {
        // ---- Wt transpose: flat view with stride 65 (bank-conflict-free) ----
        float* tf = &tile[0][0];
        int local = blk - 896;                // 0..63
        int k0 = (local & 3) * 64;
        int n0 = (local >> 2) * 64;
        int a = tid & 63, q = tid >> 6;
        #pragma unroll
        for (int i = 0; i < 16; ++i) {
            int k = q * 16 + i;
            tf[k * 65 + a] = W[(size_t)(k0 + k) * 1024 + n0 + a];
        }
        __syncthreads();
        #pragma unroll
        for (int i = 0; i < 16; ++i) {
            int n = q * 16 + i;
            Wt[(size_t)(n0 + n) * 256 + k0 + a] = to_bf16(tf[a * 65 + n]);
        }
    }
}

// ---------------- K2: MFMA in_proj GEMM, dual n-tile (xs + z) per block ----------------
// block j: XCD-chunked decode — 4 n-pairs sharing one A m-slice land on the same XCD.
// Each block stages A once and computes BOTH the xs-tile (cols n0..n0+128) and the
// z-tile (cols n0+512..n0+640): A traffic halved, barriers amortized over 2x output.
__global__ __launch_bounds__(256) void gemm1_mfma(const unsigned short* __restrict__ Abf,
                                                  const unsigned short* __restrict__ Wt,
                                                  unsigned short* __restrict__ xh,
                                                  unsigned short* __restrict__ zs) {
    __shared__ __align__(16) short Asl[128][32];
    __shared__ __align__(16) short Bs1[128][32];
    __shared__ __align__(16) short Bs2[128][32];
    int tid = threadIdx.x;
    int wv = tid >> 6, ln = tid & 63;
    int j = blockIdx.x;                 // 0..511
    int x = j & 7, s = j >> 3;
    int mt = x + 8 * (s >> 2);          // m-tile 0..127 (16 per XCD, contiguous A reuse)
    int np = s & 3;                     // n-pair 0..3
    int m0 = mt * 128;
    int n0 = np * 128;                  // xs cols; z cols = n0 + 512
    int mw = (wv & 1) * 64, nw = (wv >> 1) * 64;

    f32x4 acc1[4][4], acc2[4][4];
    #pragma unroll
    for (int i = 0; i < 4; ++i)
        #pragma unroll
        for (int jj = 0; jj < 4; ++jj) { acc1[i][jj] = (f32x4)(0.f); acc2[i][jj] = (f32x4)(0.f); }

    int srow  = ln >> 2;
    int skoff = (ln & 3) * 8;

    for (int k0 = 0; k0 < 256; k0 += 32) {
        #pragma unroll
        for (int i = 0; i < 2; ++i) {
            int jr = wv * 2 + i;
            int row = jr * 16 + srow;
            gld_lds16(&Asl[jr * 16][0], &Abf[(size_t)(m0 + row) * 256 + k0 + skoff]);
            gld_lds16(&Bs1[jr * 16][0], &Wt [(size_t)(n0 + row) * 256 + k0 + skoff]);
            gld_lds16(&Bs2[jr * 16][0], &Wt [(size_t)(n0 + 512 + row) * 256 + k0 + skoff]);
        }
        __syncthreads();
        bf16x8 af[4], b1f[4], b2f[4];
        int fm = ln & 15, fk = (ln >> 4) * 8;
        #pragma unroll
        for (int i = 0; i < 4; ++i) {
            af[i]  = *(const bf16x8*)&Asl[mw + i * 16 + fm][fk];
            b1f[i] = *(const bf16x8*)&Bs1[nw + i * 16 + fm][fk];
            b2f[i] = *(const bf16x8*)&Bs2[nw + i * 16 + fm][fk];
        }
        #pragma unroll
        for (int i = 0; i < 4; ++i)
            #pragma unroll
            for (int jj = 0; jj < 4; ++jj) {
                acc1[i][jj] = __builtin_amdgcn_mfma_f32_16x16x32_bf16(af[i], b1f[jj], acc1[i][jj], 0, 0, 0);
                acc2[i][jj] = __builtin_amdgcn_mfma_f32_16x16x32_bf16(af[i], b2f[jj], acc2[i][jj], 0, 0, 0);
            }
        __syncthreads();
    }
    int ccol = ln & 15, crow = (ln >> 4) * 4;
    #pragma unroll
    for (int i = 0; i < 4; ++i) {
        #pragma unroll
        for (int jj = 0; jj < 4; ++jj) {
            int n = n0 + nw + jj * 16 + ccol;
            #pragma unroll
            for (int r = 0; r < 4; ++r) {
                int m = m0 + mw + i * 16 + crow + r;
                xh[(size_t)m * 512 + n] = to_bf16(acc1[i][jj][r]);
                zs[(size_t)m * 512 + n] = to_bf16(silu_f(acc2[i][jj][r]));
            }
        }
    }
}

// ---------------- K3 (fused): conv + xproj-MFMA + dt/pack + scan pass 1 ----------------
// one block = one (b, chunk): 512 threads, thread d owns channel d.
// LDS reads via ds_read_b128 (float4), pairs extracted in-register — bit-identical math.
__global__ __launch_bounds__(512, 4) void mid_kernel(const unsigned short* __restrict__ xh,
                                                     const float* __restrict__ cw,
                                                     const float* __restrict__ cb,
                                                     const unsigned short* __restrict__ Wxpt,
                                                     const float* __restrict__ Wdt,
                                                     const float* __restrict__ dtb,
                                                     const float* __restrict__ anegp,
                                                     unsigned* __restrict__ dxp,
                                                     float* __restrict__ xdbl,
                                                     float* __restrict__ Sarr,
                                                     float* __restrict__ Harr) {
    __shared__ __align__(16) unsigned short xcs[CHUNK][520];
    __shared__ __align__(16) float xds[CHUNK][48];
    int tid = threadIdx.x;              // 0..511 == d
    int chunk = blockIdx.x & (NCH - 1);
    int b     = blockIdx.x >> 7;
    int d = tid;
    int rbase = (b << 12) + chunk * CHUNK;

    // early per-thread parameter loads (hide latency under conv)
    float4 w4 = *(const float4*)&cw[d * 4];
    float cbd = cb[d];
    float An[16];
    #pragma unroll
    for (int n = 0; n < 16; n += 4) {
        float4 v = *(const float4*)&anegp[d * 16 + n];
        An[n] = v.x; An[n+1] = v.y; An[n+2] = v.z; An[n+3] = v.w;
    }
    f32x2 wdt2[8];
    #pragma unroll
    for (int q = 0; q < 8; ++q) {
        wdt2[q].x = Wdt[(2 * q) * 512 + d];
        wdt2[q].y = Wdt[(2 * q + 1) * 512 + d];
    }
    float bd = dtb[d];

    // ---- conv k=4 + silu, sliding window over 35 rows of xh ----
    float x0 = 0.f, x1 = 0.f, x2 = 0.f;
    if (chunk > 0) {   // chunks never cross a batch; chunk==0 -> zero left halo
        x0 = bf2f(xh[(size_t)(rbase - 3) * 512 + d]);
        x1 = bf2f(xh[(size_t)(rbase - 2) * 512 + d]);
        x2 = bf2f(xh[(size_t)(rbase - 1) * 512 + d]);
    }
    #pragma unroll
    for (int t = 0; t < CHUNK; ++t) {
        float x3 = bf2f(xh[(size_t)(rbase + t) * 512 + d]);
        float a = x0 * w4.x + x1 * w4.y + x2 * w4.z + x3 * w4.w + cbd;
        xcs[t][d] = to_bf16(silu_f(a));
        x0 = x1; x1 = x2; x2 = x3;
    }
    __syncthreads();

    // ---- xproj MFMA: waves 0..5 each own one 16x16 tile of xds[32][48] ----
    {
        int wv = tid >> 6, ln = tid & 63;
        if (wv < 6) {
            int mt = (wv >= 3) ? 16 : 0;
            int wr = (wv >= 3) ? wv - 3 : wv;
            int nt = wr * 16;
            int fm = ln & 15, fk = (ln >> 4) * 8;
            f32x4 acc = (f32x4)(0.f);
            #pragma unroll 4
            for (int k0 = 0; k0 < 512; k0 += 32) {
                bf16x8 af  = *(const bf16x8*)&xcs[mt + fm][k0 + fk];
                bf16x8 bf_ = *(const bf16x8*)&Wxpt[(size_t)(nt + fm) * 512 + k0 + fk];
                acc = __builtin_amdgcn_mfma_f32_16x16x32_bf16(af, bf_, acc, 0, 0, 0);
            }
            int ccol = ln & 15, crow = (ln >> 4) * 4;
            #pragma unroll
            for (int r = 0; r < 4; ++r)
                xds[mt + crow + r][nt + ccol] = acc[r];
        }
    }
    __syncthreads();

    // ---- write B,C (cols 16..48) to global xdbl[NR][32] for pass3 ----
    #pragma unroll
    for (int i = 0; i < 2; ++i) {
        int idx = tid + i * 512;          // 0..1023 = t*32+n, fully coalesced
        int t = idx >> 5, n = idx & 31;
        xdbl[(size_t)(rbase + t) * 32 + n] = xds[t][16 + n];
    }

    // ---- dt + softplus + pack + in-register chunk scan (pass 1), b128 LDS reads ----
    bool pm = pow_ok16(An);
    f32x2 h2[8];
    #pragma unroll
    for (int n = 0; n < 8; ++n) h2[n] = (f32x2)(0.f);
    float S = 0.f;
    const float4* xds4 = (const float4*)&xds[0][0];   // [32][12]
    if (pm) {
        float An0 = An[0];
        #pragma unroll 4
        for (int t = 0; t < CHUNK; ++t) {
            float4 q0 = xds4[t * 12 + 0], q1 = xds4[t * 12 + 1];
            float4 q2 = xds4[t * 12 + 2], q3 = xds4[t * 12 + 3];
            f32x2 acc2 = { bd, 0.f };
            acc2 = acc2 + (f32x2){q0.x, q0.y} * wdt2[0];
            acc2 = acc2 + (f32x2){q0.z, q0.w} * wdt2[1];
            acc2 = acc2 + (f32x2){q1.x, q1.y} * wdt2[2];
            acc2 = acc2 + (f32x2){q1.z, q1.w} * wdt2[3];
            acc2 = acc2 + (f32x2){q2.x, q2.y} * wdt2[4];
            acc2 = acc2 + (f32x2){q2.z, q2.w} * wdt2[5];
            acc2 = acc2 + (f32x2){q3.x, q3.y} * wdt2[6];
            acc2 = acc2 + (f32x2){q3.z, q3.w} * wdt2[7];
            float a = acc2.x + acc2.y;
            unsigned short dbf = to_bf16(softplus_f(a));
            unsigned short xbf = xcs[t][d];
            float dv = bf2f(dbf), xv = bf2f(xbf);
            dxp[(size_t)(rbase + t) * 512 + d] = (unsigned)dbf | ((unsigned)xbf << 16);
            float dx = dv * xv;
            S += dv;
            f32x2 a2[8];
            pow_chain16_pk(__expf(dv * An0), a2);
            float4 B0 = xds4[t * 12 + 4], B1 = xds4[t * 12 + 5];
            float4 B2 = xds4[t * 12 + 6], B3 = xds4[t * 12 + 7];
            h2[0] = h2[0] * a2[0] + dx * (f32x2){B0.x, B0.y};
            h2[1] = h2[1] * a2[1] + dx * (f32x2){B0.z, B0.w};
            h2[2] = h2[2] * a2[2] + dx * (f32x2){B1.x, B1.y};
            h2[3] = h2[3] * a2[3] + dx * (f32x2){B1.z, B1.w};
            h2[4] = h2[4] * a2[4] + dx * (f32x2){B2.x, B2.y};
            h2[5] = h2[5] * a2[5] + dx * (f32x2){B2.z, B2.w};
            h2[6] = h2[6] * a2[6] + dx * (f32x2){B3.x, B3.y};
            h2[7] = h2[7] * a2[7] + dx * (f32x2){B3.z, B3.w};
        }
    } else {
        #pragma unroll 2
        for (int t = 0; t < CHUNK; ++t) {
            float4 q0 = xds4[t * 12 + 0], q1 = xds4[t * 12 + 1];
            float4 q2 = xds4[t * 12 + 2], q3 = xds4[t * 12 + 3];
            f32x2 acc2 = { bd, 0.f };
            acc2 = acc2 + (f32x2){q0.x, q0.y} * wdt2[0];
            acc2 = acc2 + (f32x2){q0.z, q0.w} * wdt2[1];
            acc2 = acc2 + (f32x2){q1.x, q1.y} * wdt2[2];
            acc2 = acc2 + (f32x2){q1.z, q1.w} * wdt2[3];
            acc2 = acc2 + (f32x2){q2.x, q2.y} * wdt2[4];
            acc2 = acc2 + (f32x2){q2.z, q2.w} * wdt2[5];
            acc2 = acc2 + (f32x2){q3.x, q3.y} * wdt2[6];
            acc2 = acc2 + (f32x2){q3.z, q3.w} * wdt2[7];
            float a = acc2.x + acc2.y;
            unsigned short dbf = to_bf16(softplus_f(a));
            unsigned short xbf = xcs[t][d];
            float dv = bf2f(dbf), xv = bf2f(xbf);
            dxp[(size_t)(rbase + t) * 512 + d] = (unsigned)dbf | ((unsigned)xbf << 16);
            float dx = dv * xv;
            S += dv;
            float4 B0 = xds4[t * 12 + 4], B1 = xds4[t * 12 + 5];
            float4 B2 = xds4[t * 12 + 6], B3 = xds4[t * 12 + 7];
            f32x2 e0 = { __expf(dv * An[0]),  __expf(dv * An[1])  };
            f32x2 e1 = { __expf(dv * An[2]),  __expf(dv * An[3])  };
            f32x2 e2 = { __expf(dv * An[4]),  __expf(dv * An[5])  };
            f32x2 e3 = { __expf(dv * An[6]),  __expf(dv * An[7])  };
            f32x2 e4 = { __expf(dv * An[8]),  __expf(dv * An[9])  };
            f32x2 e5 = { __expf(dv * An[10]), __expf(dv * An[11]) };
            f32x2 e6 = { __expf(dv * An[12]), __expf(dv * An[13]) };
            f32x2 e7 = { __expf(dv * An[14]), __expf(dv * An[15]) };
            h2[0] = h2[0] * e0 + dx * (f32x2){B0.x, B0.y};
            h2[1] = h2[1] * e1 + dx * (f32x2){B0.z, B0.w};
            h2[2] = h2[2] * e2 + dx * (f32x2){B1.x, B1.y};
            h2[3] = h2[3] * e3 + dx * (f32x2){B1.z, B1.w};
            h2[4] = h2[4] * e4 + dx * (f32x2){B2.x, B2.y};
            h2[5] = h2[5] * e5 + dx * (f32x2){B2.z, B2.w};
            h2[6] = h2[6] * e6 + dx * (f32x2){B3.x, B3.y};
            h2[7] = h2[7] * e7 + dx * (f32x2){B3.z, B3.w};
        }
    }
    Sarr[(size_t)chunk * 2048 + b * 512 + d] = S;
    size_t gbase = ((size_t)(b * 512 + d)) * 16;
    size_t coff  = (size_t)chunk * 32768;
    #pragma unroll
    for (int n = 0; n < 4; ++n) {
        *(float4*)&Harr[coff + gbase + n * 4] =
            make_float4(h2[2*n].x, h2[2*n].y, h2[2*n+1].x, h2[2*n+1].y);
    }
}

// ---------------- K4: scan pass 2 (carry across chunks; P = exp(S*An)) ----------------
// 256 blocks x 128 threads: all 256 CUs active.
__global__ __launch_bounds__(128) void scan_pass2(const float* __restrict__ Sarr,
                                                  const float* __restrict__ anegp,
                                                  float* __restrict__ Harr) {
    int gid = blockIdx.x * 128 + threadIdx.x;   // 32768 = b*8192 + d*16 + n
    float An = anegp[gid & 8191];
    int sidx = gid >> 4;                        // b*512 + d
    float carry = 0.f;
    #pragma unroll 8
    for (int c = 0; c < NCH; ++c) {
        float S  = Sarr[(size_t)c * 2048 + sidx];
        size_t off = (size_t)c * 32768 + gid;
        float he = Harr[off];
        Harr[off] = carry;
        carry = he + __expf(S * An) * carry;
    }
}

// ---------------- K5 (fused): scan pass 3 + out GEMM ----------------
// one block = one (b, chunk): 512 threads, thread d owns channel d.
// B/C read from LDS via float4 (ds_read_b128), pairs extracted in-register.
__global__ __launch_bounds__(512, 4) void scan_pass3_out(const unsigned* __restrict__ dxp,
                                                         const unsigned short* __restrict__ zs,
                                                         const float* __restrict__ xdbl,
                                                         const float* __restrict__ anegp,
                                                         const float* __restrict__ Dp,
                                                         const float* __restrict__ Hin,
                                                         const unsigned short* __restrict__ WcT,
                                                         const float* __restrict__ bo,
                                                         float* __restrict__ out) {
    __shared__ __align__(16) unsigned short yl[CHUNK][520];
    __shared__ __align__(16) float4 sB4[CHUNK][4];
    __shared__ __align__(16) float4 sC4[CHUNK][4];
    int tid = threadIdx.x;
    int chunk = blockIdx.x & (NCH - 1);
    int b     = blockIdx.x >> 7;
    int d = tid;
    int rbase = (b << 12) + chunk * CHUNK;
    unsigned pwv[CHUNK];
    #pragma unroll
    for (int t = 0; t < CHUNK; ++t)
        pwv[t] = dxp[(size_t)(rbase + t) * 512 + d];
    {
        float* sBf = (float*)sB4;
        float* sCf = (float*)sC4;
        int t = tid >> 4, n = tid & 15;      // 512 threads cover 32x16, 1 B + 1 C each
        sBf[t * 16 + n] = xdbl[(size_t)(rbase + t) * 32 + n];
        sCf[t * 16 + n] = xdbl[(size_t)(rbase + t) * 32 + 16 + n];
    }
    float An[16];
    #pragma unroll
    for (int n = 0; n < 16; n += 4) {
        float4 v = *(const float4*)&anegp[d * 16 + n];
        An[n] = v.x; An[n+1] = v.y; An[n+2] = v.z; An[n+3] = v.w;
    }
    bool pm = pow_ok16(An);
    float Dv = Dp[d];
    __syncthreads();
    size_t gbase = ((size_t)(b * 512 + d)) * 16;
    size_t coff  = (size_t)chunk * 32768;
    f32x2 h2[8];
    #pragma unroll
    for (int n = 0; n < 4; ++n) {
        float4 v = *(const float4*)&Hin[coff + gbase + n * 4];
        h2[2*n].x = v.x; h2[2*n].y = v.y; h2[2*n+1].x = v.z; h2[2*n+1].y = v.w;
    }
    if (pm) {
        float An0 = An[0];
        #pragma unroll 8
        for (int t = 0; t < CHUNK; ++t) {
            unsigned pw = pwv[t];
            float dv = bf2f((unsigned short)(pw & 0xffffu));
            float xv = bf2f((unsigned short)(pw >> 16));
            float zv = bf2f(zs[(size_t)(rbase + t) * 512 + d]);
            float dx = dv * xv;
            f32x2 a2[8];
            pow_chain16_pk(__expf(dv * An0), a2);
            float4 B0 = sB4[t][0], B1 = sB4[t][1], B2 = sB4[t][2], B3 = sB4[t][3];
            float4 C0 = sC4[t][0], C1 = sC4[t][1], C2 = sC4[t][2], C3 = sC4[t][3];
            f32x2 y2 = (f32x2)(0.f);
            h2[0] = h2[0] * a2[0] + dx * (f32x2){B0.x, B0.y};  y2 = y2 + h2[0] * (f32x2){C0.x, C0.y};
            h2[1] = h2[1] * a2[1] + dx * (f32x2){B0.z, B0.w};  y2 = y2 + h2[1] * (f32x2){C0.z, C0.w};
            h2[2] = h2[2] * a2[2] + dx * (f32x2){B1.x, B1.y};  y2 = y2 + h2[2] * (f32x2){C1.x, C1.y};
            h2[3] = h2[3] * a2[3] + dx * (f32x2){B1.z, B1.w};  y2 = y2 + h2[3] * (f32x2){C1.z, C1.w};
            h2[4] = h2[4] * a2[4] + dx * (f32x2){B2.x, B2.y};  y2 = y2 + h2[4] * (f32x2){C2.x, C2.y};
            h2[5] = h2[5] * a2[5] + dx * (f32x2){B2.z, B2.w};  y2 = y2 + h2[5] * (f32x2){C2.z, C2.w};
            h2[6] = h2[6] * a2[6] + dx * (f32x2){B3.x, B3.y};  y2 = y2 + h2[6] * (f32x2){C3.x, C3.y};
            h2[7] = h2[7] * a2[7] + dx * (f32x2){B3.z, B3.w};  y2 = y2 + h2[7] * (f32x2){C3.z, C3.w};
            float y = y2.x + y2.y + xv * Dv;
            y *= zv;
            yl[t][d] = to_bf16(y);
        }
    } else {
        #pragma unroll 4
        for (int t = 0; t < CHUNK; ++t) {
            unsigned pw = pwv[t];
            float dv = bf2f((unsigned short)(pw & 0xffffu));
            float xv = bf2f((unsigned short)(pw >> 16));
            float zv = bf2f(zs[(size_t)(rbase + t) * 512 + d]);
            float dx = dv * xv;
            float4 B0 = sB4[t][0], B1 = sB4[t][1], B2 = sB4[t][2], B3 = sB4[t][3];
            float4 C0 = sC4[t][0], C1 = sC4[t][1], C2 = sC4[t][2], C3 = sC4[t][3];
            f32x2 e0 = { __expf(dv * An[0]),  __expf(dv * An[1])  };
            f32x2 e1 = { __expf(dv * An[2]),  __expf(dv * An[3])  };
            f32x2 e2 = { __expf(dv * An[4]),  __expf(dv * An[5])  };
            f32x2 e3 = { __expf(dv * An[6]),  __expf(dv * An[7])  };
            f32x2 e4 = { __expf(dv * An[8]),  __expf(dv * An[9])  };
            f32x2 e5 = { __expf(dv * An[10]), __expf(dv * An[11]) };
            f32x2 e6 = { __expf(dv * An[12]), __expf(dv * An[13]) };
            f32x2 e7 = { __expf(dv * An[14]), __expf(dv * An[15]) };
            f32x2 y2 = (f32x2)(0.f);
            h2[0] = h2[0] * e0 + dx * (f32x2){B0.x, B0.y};  y2 = y2 + h2[0] * (f32x2){C0.x, C0.y};
            h2[1] = h2[1] * e1 + dx * (f32x2){B0.z, B0.w};  y2 = y2 + h2[1] * (f32x2){C0.z, C0.w};
            h2[2] = h2[2] * e2 + dx * (f32x2){B1.x, B1.y};  y2 = y2 + h2[2] * (f32x2){C1.x, C1.y};
            h2[3] = h2[3] * e3 + dx * (f32x2){B1.z, B1.w};  y2 = y2 + h2[3] * (f32x2){C1.z, C1.w};
            h2[4] = h2[4] * e4 + dx * (f32x2){B2.x, B2.y};  y2 = y2 + h2[4] * (f32x2){C2.x, C2.y};
            h2[5] = h2[5] * e5 + dx * (f32x2){B2.z, B2.w};  y2 = y2 + h2[5] * (f32x2){C2.z, C2.w};
            h2[6] = h2[6] * e6 + dx * (f32x2){B3.x, B3.y};  y2 = y2 + h2[6] * (f32x2){C3.x, C3.y};
            h2[7] = h2[7] * e7 + dx * (f32x2){B3.z, B3.w};  y2 = y2 + h2[7] * (f32x2){C3.z, C3.w};
            float y = y2.x + y2.y + xv * Dv;
            y *= zv;
            yl[t][d] = to_bf16(y);
        }
    }
    __syncthreads();

    // ---- out GEMM: [32 t x 128 c] = yl[32x512] @ WcT[128x512]^T ----
    {
        int wv = tid >> 6, ln = tid & 63;       // wave wv owns c-tile wv
        int fm = ln & 15, fk = (ln >> 4) * 8;
        f32x4 acc0 = (f32x4)(0.f), acc1 = (f32x4)(0.f);
        const unsigned short* wrow = &WcT[(size_t)(wv * 16 + fm) * 512];
        #pragma unroll 4
        for (int k0 = 0; k0 < 512; k0 += 32) {
            bf16x8 af = *(const bf16x8*)&wrow[k0 + fk];
            bf16x8 b0 = *(const bf16x8*)&yl[fm][k0 + fk];
            bf16x8 b1 = *(const bf16x8*)&yl[16 + fm][k0 + fk];
            acc0 = __builtin_amdgcn_mfma_f32_16x16x32_bf16(af, b0, acc0, 0, 0, 0);
            acc1 = __builtin_amdgcn_mfma_f32_16x16x32_bf16(af, b1, acc1, 0, 0, 0);
        }
        int ccol = ln & 15, crow = (ln >> 4) * 4;
        #pragma unroll
        for (int r = 0; r < 4; ++r) {
            int c = wv * 16 + crow + r;
            float bias = bo[c];
            size_t obase = ((size_t)(b * 128 + c)) * LSEQ + chunk * CHUNK;
            out[obase + ccol]      = acc0[r] + bias;
            out[obase + 16 + ccol] = acc1[r] + bias;
        }
    }
}

// ---------------- launch ----------------
extern "C" void kernel_launch(void* const* d_in, const int* in_sizes, int n_in,
                              void* d_out, int out_size, void* d_ws, size_t ws_size,
                              hipStream_t stream) {
    (void)in_sizes; (void)n_in; (void)out_size; (void)ws_size;
    const float* input    = (const float*)d_in[0];
    const float* input2   = (const float*)d_in[1];
    const float* ln_g     = (const float*)d_in[2];
    const float* ln_b     = (const float*)d_in[3];
    const float* outp_w   = (const float*)d_in[4];
    const float* outp_b   = (const float*)d_in[5];
    const float* in_proj  = (const float*)d_in[6];
    const float* conv_w   = (const float*)d_in[7];
    const float* conv_b   = (const float*)d_in[8];
    const float* x_proj   = (const float*)d_in[9];
    const float* dt_w     = (const float*)d_in[10];
    const float* dt_b     = (const float*)d_in[11];
    const float* A_log    = (const float*)d_in[12];
    const float* D_param  = (const float*)d_in[13];
    const float* mout_w   = (const float*)d_in[14];
    float* out = (float*)d_out;

    char* ws = (char*)d_ws;
    unsigned short* xh    = (unsigned short*)ws;                    ws += (size_t)NR * 512 * 2;
    unsigned short* zsbuf = (unsigned short*)ws;                    ws += (size_t)NR * 512 * 2;
    unsigned*       dxp   = (unsigned*)ws;                          ws += (size_t)NR * 512 * 4;
    unsigned short* Abf   = (unsigned short*)ws;                    ws += (size_t)NR * 256 * 2;
    unsigned short* Wt    = (unsigned short*)ws;                    ws += (size_t)1024 * 256 * 2;
    unsigned short* WcT   = (unsigned short*)ws;                    ws += (size_t)128 * 512 * 2;
    unsigned short* Wxpt  = (unsigned short*)ws;                    ws += (size_t)48 * 512 * 2;
    float* anegp = (float*)ws;                                      ws += (size_t)512 * 16 * 4;
    float* xdbl = (float*)ws;                                       ws += (size_t)NR * 32 * 4;
    float* Sarr = (float*)ws;                                       ws += (size_t)NCH * 2048 * 4;
    float* Harr = (float*)ws;                                       ws += (size_t)NCH * 32768 * 4;

    front_kernel<<<960, 256, 0, stream>>>(input, input2, ln_g, ln_b, mout_w, outp_w,
                                          x_proj, A_log, in_proj,
                                          Abf, WcT, Wxpt, anegp, Wt);
    gemm1_mfma<<<512, 256, 0, stream>>>(Abf, Wt, xh, zsbuf);
    mid_kernel<<<NB * NCH, 512, 0, stream>>>(xh, conv_w, conv_b, Wxpt, dt_w, dt_b,
                                             anegp, dxp, xdbl, Sarr, Harr);
    scan_pass2<<<256, 128, 0, stream>>>(Sarr, anegp, Harr);
    scan_pass3_out<<<NB * NCH, 512, 0, stream>>>(dxp, zsbuf, xdbl, anegp, D_param,
                                                 Harr, WcT, outp_b, out);
}

// Round 13
// 195.616 us; speedup vs baseline: 1.0320x; 1.0320x over previous
//
#include <hip/hip_runtime.h>
#include <hip/hip_bf16.h>
#include <math.h>

#define LSEQ 4096
#define NR   16384   // B*L
#define NB   4
#define CHUNK 32
#define NCH  128

typedef short bf16x8 __attribute__((ext_vector_type(8)));
typedef float f32x4  __attribute__((ext_vector_type(4)));
typedef float f32x2  __attribute__((ext_vector_type(2)));

typedef __attribute__((address_space(1))) const void gvoid_t;
typedef __attribute__((address_space(3))) void svoid_t;

__device__ __forceinline__ void gld_lds16(void* lds, const void* g) {
    __builtin_amdgcn_global_load_lds((gvoid_t*)g, (svoid_t*)lds, 16, 0, 0);
}

__device__ __forceinline__ unsigned short to_bf16(float f) {
    union { float f; unsigned u; } x; x.f = f;
    unsigned r = (x.u + 0x7fff + ((x.u >> 16) & 1)) >> 16;
    return (unsigned short)r;
}
__device__ __forceinline__ float bf2f(unsigned short u) {
    union { unsigned u; float f; } x; x.u = ((unsigned)u) << 16;
    return x.f;
}
__device__ __forceinline__ float softplus_f(float x) {
    return x > 20.f ? x : __logf(1.f + __expf(x));
}
__device__ __forceinline__ float silu_f(float x) {
    return x / (1.f + __expf(-x));
}

// packed pow chain: a2[i] = {r^(2i+1), r^(2i+2)} — bit-identical mult trees to scalar version
__device__ __forceinline__ void pow_chain16_pk(float r, f32x2* a2) {
    float r2 = r * r;
    float r4 = r2 * r2;
    float r8 = r4 * r4;
    f32x2 v01 = { r, r2 };
    a2[0] = v01;
    a2[1] = v01 * r2;    // r3,  r4
    a2[2] = v01 * r4;    // r5,  r6
    a2[3] = a2[1] * r4;  // r7,  r8
    a2[4] = v01 * r8;    // r9,  r10
    a2[5] = a2[1] * r8;  // r11, r12
    a2[6] = a2[2] * r8;  // r13, r14
    a2[7] = a2[3] * r8;  // r15, r16
}

// per-thread check: An[n] == (n+1) * An[0] for all n (power-structure of A)
__device__ __forceinline__ bool pow_ok16(const float* An) {
    bool ok = true;
    #pragma unroll
    for (int n = 1; n < 16; ++n) {
        float ref = (float)(n + 1) * An[0];
        ok = ok && (fabsf(An[n] - ref) <= 1e-4f * fabsf(An[n]) + 1e-30f);
    }
    return ok;
}

// ---------------- K1: merged front (ln | wct | wxpt | aneg | Wt-transpose) ----------------
__global__ __launch_bounds__(256) void front_kernel(const float* __restrict__ in1,
                                                    const float* __restrict__ in2,
                                                    const float* __restrict__ g,
                                                    const float* __restrict__ beta,
                                                    const float* __restrict__ Wm,
                                                    const float* __restrict__ Wo,
                                                    const float* __restrict__ Wxp,
                                                    const float* __restrict__ A_log,
                                                    const float* __restrict__ W,
                                                    unsigned short* __restrict__ Abf,
                                                    unsigned short* __restrict__ WcT,
                                                    unsigned short* __restrict__ Wxpt,
                                                    float* __restrict__ anegp,
                                                    unsigned short* __restrict__ Wt) {
    __shared__ float tile[256][33];   // 8448 floats; transpose branch uses flat 64*65=4160
    int blk = blockIdx.x;
    int tid = threadIdx.x;
    if (blk < 512) {
        // ---- layernorm + transpose + bf16 ----
        __shared__ float s1[8][32], s2[8][32];
        __shared__ float smu[32], srs[32];
        int b  = blk >> 7;
        int t0 = (blk & 127) * 32;
        #pragma unroll
        for (int p = 0; p < 8; ++p) {
            int c = p * 32 + (tid >> 3);
            int toff = (tid & 7) * 4;
            const float* src = (c < 128) ? &in1[((size_t)(b * 128 + c)) * LSEQ + t0 + toff]
                                         : &in2[((size_t)(b * 128 + (c - 128))) * LSEQ + t0 + toff];
            float4 v = *(const float4*)src;
            tile[c][toff] = v.x; tile[c][toff+1] = v.y;
            tile[c][toff+2] = v.z; tile[c][toff+3] = v.w;
        }
        __syncthreads();
        {
            int t = tid & 31, gg = tid >> 5;
            float a1 = 0.f, a2 = 0.f;
            #pragma unroll
            for (int i = 0; i < 32; ++i) {
                float v = tile[gg * 32 + i][t];
                a1 += v; a2 += v * v;
            }
            s1[gg][t] = a1; s2[gg][t] = a2;
        }
        __syncthreads();
        if (tid < 32) {
            float a1 = 0.f, a2 = 0.f;
            #pragma unroll
            for (int gg = 0; gg < 8; ++gg) { a1 += s1[gg][tid]; a2 += s2[gg][tid]; }
            float m = a1 * (1.f / 256.f);
            float var = a2 * (1.f / 256.f) - m * m;
            smu[tid] = m;
            srs[tid] = rsqrtf(var + 1e-5f);
        }
        __syncthreads();
        int c = tid;
        float gc = g[c], bc = beta[c];
        #pragma unroll 4
        for (int t = 0; t < 32; ++t) {
            float v = (tile[c][t] - smu[t]) * srs[t] * gc + bc;
            Abf[((size_t)((b << 12) + t0 + t)) * 256 + c] = to_bf16(v);
        }
    } else if (blk < 768) {
        int gid = (blk - 512) * 256 + tid;    // 65536
        int row = gid >> 7, col = gid & 127;
        float acc = 0.f;
        #pragma unroll 8
        for (int k = 0; k < 256; ++k) acc += Wm[row * 256 + k] * Wo[k * 128 + col];
        WcT[(size_t)col * 512 + row] = to_bf16(acc);
    } else if (blk < 864) {
        int gid = (blk - 768) * 256 + tid;    // 24576
        int n = gid >> 9, k = gid & 511;
        Wxpt[gid] = to_bf16(Wxp[(size_t)k * 48 + n]);
    } else if (blk < 896) {
        int gid = (blk - 864) * 256 + tid;    // 8192
        anegp[gid] = -__expf(A_log[gid]);
    } else {
        // ---- Wt transpose: flat view with stride 65 (bank-conflict-free) ----
        float* tf = &tile[0][0];
        int local = blk - 896;                // 0..63
        int k0 = (local & 3) * 64;
        int n0 = (local >> 2) * 64;
        int a = tid & 63, q = tid >> 6;
        #pragma unroll
        for (int i = 0; i < 16; ++i) {
            int k = q * 16 + i;
            tf[k * 65 + a] = W[(size_t)(k0 + k) * 1024 + n0 + a];
        }
        __syncthreads();
        #pragma unroll
        for (int i = 0; i < 16; ++i) {
            int n = q * 16 + i;
            Wt[(size_t)(n0 + n) * 256 + k0 + a] = to_bf16(tf[a * 65 + n]);
        }
    }
}

// ---------------- K2: MFMA in_proj GEMM, silu on z half, bf16 out ----------------
// launch_bounds(256,4): min 4 waves/EU -> 4 blocks/CU capacity (VGPR capped at 128).
// gemm1 is latency-bound (R11 counters: MfmaUtil 5%, HBM 10%, Occ 10% at VGPR 160);
// more resident blocks overlap one block's MFMA with another's vmcnt(0) drain.
__global__ __launch_bounds__(256, 4) void gemm1_mfma(const unsigned short* __restrict__ Abf,
                                                     const unsigned short* __restrict__ Wt,
                                                     unsigned short* __restrict__ xh,
                                                     unsigned short* __restrict__ zs) {
    __shared__ __align__(16) short Asl[128][32];
    __shared__ __align__(16) short Bsl[128][32];
    int tid = threadIdx.x;
    int wv = tid >> 6, ln = tid & 63;
    int m0 = blockIdx.x * 128;
    int n0 = blockIdx.y * 128;
    int mw = (wv & 1) * 64, nw = (wv >> 1) * 64;

    f32x4 acc[4][4];
    #pragma unroll
    for (int i = 0; i < 4; ++i)
        #pragma unroll
        for (int j = 0; j < 4; ++j) acc[i][j] = (f32x4)(0.f);

    int srow  = ln >> 2;
    int skoff = (ln & 3) * 8;

    for (int k0 = 0; k0 < 256; k0 += 32) {
        #pragma unroll
        for (int i = 0; i < 2; ++i) {
            int j = wv * 2 + i;
            int row = j * 16 + srow;
            gld_lds16(&Asl[j * 16][0], &Abf[(size_t)(m0 + row) * 256 + k0 + skoff]);
            gld_lds16(&Bsl[j * 16][0], &Wt [(size_t)(n0 + row) * 256 + k0 + skoff]);
        }
        __syncthreads();
        bf16x8 af[4], bff[4];
        int fm = ln & 15, fk = (ln >> 4) * 8;
        #pragma unroll
        for (int i = 0; i < 4; ++i) {
            af[i]  = *(const bf16x8*)&Asl[mw + i * 16 + fm][fk];
            bff[i] = *(const bf16x8*)&Bsl[nw + i * 16 + fm][fk];
        }
        #pragma unroll
        for (int i = 0; i < 4; ++i)
            #pragma unroll
            for (int j = 0; j < 4; ++j)
                acc[i][j] = __builtin_amdgcn_mfma_f32_16x16x32_bf16(af[i], bff[j], acc[i][j], 0, 0, 0);
        __syncthreads();
    }
    int ccol = ln & 15, crow = (ln >> 4) * 4;
    bool zhalf = (n0 >= 512);
    #pragma unroll
    for (int i = 0; i < 4; ++i) {
        #pragma unroll
        for (int j = 0; j < 4; ++j) {
            int n = n0 + nw + j * 16 + ccol;
            #pragma unroll
            for (int r = 0; r < 4; ++r) {
                int m = m0 + mw + i * 16 + crow + r;
                float v = acc[i][j][r];
                if (zhalf) zs[(size_t)m * 512 + (n - 512)] = to_bf16(silu_f(v));
                else       xh[(size_t)m * 512 + n]         = to_bf16(v);
            }
        }
    }
}

// ---------------- K3 (fused): conv + xproj-MFMA + dt/pack + scan pass 1 ----------------
// one block = one (b, chunk): 512 threads, thread d owns channel d.
// LDS reads via ds_read_b128 (float4), pairs extracted in-register — bit-identical math.
__global__ __launch_bounds__(512, 4) void mid_kernel(const unsigned short* __restrict__ xh,
                                                     const float* __restrict__ cw,
                                                     const float* __restrict__ cb,
                                                     const unsigned short* __restrict__ Wxpt,
                                                     const float* __restrict__ Wdt,
                                                     const float* __restrict__ dtb,
                                                     const float* __restrict__ anegp,
                                                     unsigned* __restrict__ dxp,
                                                     float* __restrict__ xdbl,
                                                     float* __restrict__ Sarr,
                                                     float* __restrict__ Harr) {
    __shared__ __align__(16) unsigned short xcs[CHUNK][520];
    __shared__ __align__(16) float xds[CHUNK][48];
    int tid = threadIdx.x;              // 0..511 == d
    int chunk = blockIdx.x & (NCH - 1);
    int b     = blockIdx.x >> 7;
    int d = tid;
    int rbase = (b << 12) + chunk * CHUNK;

    // early per-thread parameter loads (hide latency under conv)
    float4 w4 = *(const float4*)&cw[d * 4];
    float cbd = cb[d];
    float An[16];
    #pragma unroll
    for (int n = 0; n < 16; n += 4) {
        float4 v = *(const float4*)&anegp[d * 16 + n];
        An[n] = v.x; An[n+1] = v.y; An[n+2] = v.z; An[n+3] = v.w;
    }
    f32x2 wdt2[8];
    #pragma unroll
    for (int q = 0; q < 8; ++q) {
        wdt2[q].x = Wdt[(2 * q) * 512 + d];
        wdt2[q].y = Wdt[(2 * q + 1) * 512 + d];
    }
    float bd = dtb[d];

    // ---- conv k=4 + silu, sliding window over 35 rows of xh ----
    float x0 = 0.f, x1 = 0.f, x2 = 0.f;
    if (chunk > 0) {   // chunks never cross a batch; chunk==0 -> zero left halo
        x0 = bf2f(xh[(size_t)(rbase - 3) * 512 + d]);
        x1 = bf2f(xh[(size_t)(rbase - 2) * 512 + d]);
        x2 = bf2f(xh[(size_t)(rbase - 1) * 512 + d]);
    }
    #pragma unroll
    for (int t = 0; t < CHUNK; ++t) {
        float x3 = bf2f(xh[(size_t)(rbase + t) * 512 + d]);
        float a = x0 * w4.x + x1 * w4.y + x2 * w4.z + x3 * w4.w + cbd;
        xcs[t][d] = to_bf16(silu_f(a));
        x0 = x1; x1 = x2; x2 = x3;
    }
    __syncthreads();

    // ---- xproj MFMA: waves 0..5 each own one 16x16 tile of xds[32][48] ----
    {
        int wv = tid >> 6, ln = tid & 63;
        if (wv < 6) {
            int mt = (wv >= 3) ? 16 : 0;
            int wr = (wv >= 3) ? wv - 3 : wv;
            int nt = wr * 16;
            int fm = ln & 15, fk = (ln >> 4) * 8;
            f32x4 acc = (f32x4)(0.f);
            #pragma unroll 4
            for (int k0 = 0; k0 < 512; k0 += 32) {
                bf16x8 af  = *(const bf16x8*)&xcs[mt + fm][k0 + fk];
                bf16x8 bf_ = *(const bf16x8*)&Wxpt[(size_t)(nt + fm) * 512 + k0 + fk];
                acc = __builtin_amdgcn_mfma_f32_16x16x32_bf16(af, bf_, acc, 0, 0, 0);
            }
            int ccol = ln & 15, crow = (ln >> 4) * 4;
            #pragma unroll
            for (int r = 0; r < 4; ++r)
                xds[mt + crow + r][nt + ccol] = acc[r];
        }
    }
    __syncthreads();

    // ---- write B,C (cols 16..48) to global xdbl[NR][32] for pass3 ----
    #pragma unroll
    for (int i = 0; i < 2; ++i) {
        int idx = tid + i * 512;          // 0..1023 = t*32+n, fully coalesced
        int t = idx >> 5, n = idx & 31;
        xdbl[(size_t)(rbase + t) * 32 + n] = xds[t][16 + n];
    }

    // ---- dt + softplus + pack + in-register chunk scan (pass 1), b128 LDS reads ----
    bool pm = pow_ok16(An);
    f32x2 h2[8];
    #pragma unroll
    for (int n = 0; n < 8; ++n) h2[n] = (f32x2)(0.f);
    float S = 0.f;
    const float4* xds4 = (const float4*)&xds[0][0];   // [32][12]
    if (pm) {
        float An0 = An[0];
        #pragma unroll 4
        for (int t = 0; t < CHUNK; ++t) {
            float4 q0 = xds4[t * 12 + 0], q1 = xds4[t * 12 + 1];
            float4 q2 = xds4[t * 12 + 2], q3 = xds4[t * 12 + 3];
            f32x2 acc2 = { bd, 0.f };
            acc2 = acc2 + (f32x2){q0.x, q0.y} * wdt2[0];
            acc2 = acc2 + (f32x2){q0.z, q0.w} * wdt2[1];
            acc2 = acc2 + (f32x2){q1.x, q1.y} * wdt2[2];
            acc2 = acc2 + (f32x2){q1.z, q1.w} * wdt2[3];
            acc2 = acc2 + (f32x2){q2.x, q2.y} * wdt2[4];
            acc2 = acc2 + (f32x2){q2.z, q2.w} * wdt2[5];
            acc2 = acc2 + (f32x2){q3.x, q3.y} * wdt2[6];
            acc2 = acc2 + (f32x2){q3.z, q3.w} * wdt2[7];
            float a = acc2.x + acc2.y;
            unsigned short dbf = to_bf16(softplus_f(a));
            unsigned short xbf = xcs[t][d];
            float dv = bf2f(dbf), xv = bf2f(xbf);
            dxp[(size_t)(rbase + t) * 512 + d] = (unsigned)dbf | ((unsigned)xbf << 16);
            float dx = dv * xv;
            S += dv;
            f32x2 a2[8];
            pow_chain16_pk(__expf(dv * An0), a2);
            float4 B0 = xds4[t * 12 + 4], B1 = xds4[t * 12 + 5];
            float4 B2 = xds4[t * 12 + 6], B3 = xds4[t * 12 + 7];
            h2[0] = h2[0] * a2[0] + dx * (f32x2){B0.x, B0.y};
            h2[1] = h2[1] * a2[1] + dx * (f32x2){B0.z, B0.w};
            h2[2] = h2[2] * a2[2] + dx * (f32x2){B1.x, B1.y};
            h2[3] = h2[3] * a2[3] + dx * (f32x2){B1.z, B1.w};
            h2[4] = h2[4] * a2[4] + dx * (f32x2){B2.x, B2.y};
            h2[5] = h2[5] * a2[5] + dx * (f32x2){B2.z, B2.w};
            h2[6] = h2[6] * a2[6] + dx * (f32x2){B3.x, B3.y};
            h2[7] = h2[7] * a2[7] + dx * (f32x2){B3.z, B3.w};
        }
    } else {
        #pragma unroll 2
        for (int t = 0; t < CHUNK; ++t) {
            float4 q0 = xds4[t * 12 + 0], q1 = xds4[t * 12 + 1];
            float4 q2 = xds4[t * 12 + 2], q3 = xds4[t * 12 + 3];
            f32x2 acc2 = { bd, 0.f };
            acc2 = acc2 + (f32x2){q0.x, q0.y} * wdt2[0];
            acc2 = acc2 + (f32x2){q0.z, q0.w} * wdt2[1];
            acc2 = acc2 + (f32x2){q1.x, q1.y} * wdt2[2];
            acc2 = acc2 + (f32x2){q1.z, q1.w} * wdt2[3];
            acc2 = acc2 + (f32x2){q2.x, q2.y} * wdt2[4];
            acc2 = acc2 + (f32x2){q2.z, q2.w} * wdt2[5];
            acc2 = acc2 + (f32x2){q3.x, q3.y} * wdt2[6];
            acc2 = acc2 + (f32x2){q3.z, q3.w} * wdt2[7];
            float a = acc2.x + acc2.y;
            unsigned short dbf = to_bf16(softplus_f(a));
            unsigned short xbf = xcs[t][d];
            float dv = bf2f(dbf), xv = bf2f(xbf);
            dxp[(size_t)(rbase + t) * 512 + d] = (unsigned)dbf | ((unsigned)xbf << 16);
            float dx = dv * xv;
            S += dv;
            float4 B0 = xds4[t * 12 + 4], B1 = xds4[t * 12 + 5];
            float4 B2 = xds4[t * 12 + 6], B3 = xds4[t * 12 + 7];
            f32x2 e0 = { __expf(dv * An[0]),  __expf(dv * An[1])  };
            f32x2 e1 = { __expf(dv * An[2]),  __expf(dv * An[3])  };
            f32x2 e2 = { __expf(dv * An[4]),  __expf(dv * An[5])  };
            f32x2 e3 = { __expf(dv * An[6]),  __expf(dv * An[7])  };
            f32x2 e4 = { __expf(dv * An[8]),  __expf(dv * An[9])  };
            f32x2 e5 = { __expf(dv * An[10]), __expf(dv * An[11]) };
            f32x2 e6 = { __expf(dv * An[12]), __expf(dv * An[13]) };
            f32x2 e7 = { __expf(dv * An[14]), __expf(dv * An[15]) };
            h2[0] = h2[0] * e0 + dx * (f32x2){B0.x, B0.y};
            h2[1] = h2[1] * e1 + dx * (f32x2){B0.z, B0.w};
            h2[2] = h2[2] * e2 + dx * (f32x2){B1.x, B1.y};
            h2[3] = h2[3] * e3 + dx * (f32x2){B1.z, B1.w};
            h2[4] = h2[4] * e4 + dx * (f32x2){B2.x, B2.y};
            h2[5] = h2[5] * e5 + dx * (f32x2){B2.z, B2.w};
            h2[6] = h2[6] * e6 + dx * (f32x2){B3.x, B3.y};
            h2[7] = h2[7] * e7 + dx * (f32x2){B3.z, B3.w};
        }
    }
    Sarr[(size_t)chunk * 2048 + b * 512 + d] = S;
    size_t gbase = ((size_t)(b * 512 + d)) * 16;
    size_t coff  = (size_t)chunk * 32768;
    #pragma unroll
    for (int n = 0; n < 4; ++n) {
        *(float4*)&Harr[coff + gbase + n * 4] =
            make_float4(h2[2*n].x, h2[2*n].y, h2[2*n+1].x, h2[2*n+1].y);
    }
}

// ---------------- K4: scan pass 2 (carry across chunks; P = exp(S*An)) ----------------
// 256 blocks x 128 threads: all 256 CUs active.
__global__ __launch_bounds__(128) void scan_pass2(const float* __restrict__ Sarr,
                                                  const float* __restrict__ anegp,
                                                  float* __restrict__ Harr) {
    int gid = blockIdx.x * 128 + threadIdx.x;   // 32768 = b*8192 + d*16 + n
    float An = anegp[gid & 8191];
    int sidx = gid >> 4;                        // b*512 + d
    float carry = 0.f;
    #pragma unroll 8
    for (int c = 0; c < NCH; ++c) {
        float S  = Sarr[(size_t)c * 2048 + sidx];
        size_t off = (size_t)c * 32768 + gid;
        float he = Harr[off];
        Harr[off] = carry;
        carry = he + __expf(S * An) * carry;
    }
}

// ---------------- K5 (fused): scan pass 3 + out GEMM ----------------
// one block = one (b, chunk): 512 threads, thread d owns channel d.
// B/C read from LDS via float4 (ds_read_b128), pairs extracted in-register.
__global__ __launch_bounds__(512, 4) void scan_pass3_out(const unsigned* __restrict__ dxp,
                                                         const unsigned short* __restrict__ zs,
                                                         const float* __restrict__ xdbl,
                                                         const float* __restrict__ anegp,
                                                         const float* __restrict__ Dp,
                                                         const float* __restrict__ Hin,
                                                         const unsigned short* __restrict__ WcT,
                                                         const float* __restrict__ bo,
                                                         float* __restrict__ out) {
    __shared__ __align__(16) unsigned short yl[CHUNK][520];
    __shared__ __align__(16) float4 sB4[CHUNK][4];
    __shared__ __align__(16) float4 sC4[CHUNK][4];
    int tid = threadIdx.x;
    int chunk = blockIdx.x & (NCH - 1);
    int b     = blockIdx.x >> 7;
    int d = tid;
    int rbase = (b << 12) + chunk * CHUNK;
    unsigned pwv[CHUNK];
    #pragma unroll
    for (int t = 0; t < CHUNK; ++t)
        pwv[t] = dxp[(size_t)(rbase + t) * 512 + d];
    {
        float* sBf = (float*)sB4;
        float* sCf = (float*)sC4;
        int t = tid >> 4, n = tid & 15;      // 512 threads cover 32x16, 1 B + 1 C each
        sBf[t * 16 + n] = xdbl[(size_t)(rbase + t) * 32 + n];
        sCf[t * 16 + n] = xdbl[(size_t)(rbase + t) * 32 + 16 + n];
    }
    float An[16];
    #pragma unroll
    for (int n = 0; n < 16; n += 4) {
        float4 v = *(const float4*)&anegp[d * 16 + n];
        An[n] = v.x; An[n+1] = v.y; An[n+2] = v.z; An[n+3] = v.w;
    }
    bool pm = pow_ok16(An);
    float Dv = Dp[d];
    __syncthreads();
    size_t gbase = ((size_t)(b * 512 + d)) * 16;
    size_t coff  = (size_t)chunk * 32768;
    f32x2 h2[8];
    #pragma unroll
    for (int n = 0; n < 4; ++n) {
        float4 v = *(const float4*)&Hin[coff + gbase + n * 4];
        h2[2*n].x = v.x; h2[2*n].y = v.y; h2[2*n+1].x = v.z; h2[2*n+1].y = v.w;
    }
    if (pm) {
        float An0 = An[0];
        #pragma unroll 8
        for (int t = 0; t < CHUNK; ++t) {
            unsigned pw = pwv[t];
            float dv = bf2f((unsigned short)(pw & 0xffffu));
            float xv = bf2f((unsigned short)(pw >> 16));
            float zv = bf2f(zs[(size_t)(rbase + t) * 512 + d]);
            float dx = dv * xv;
            f32x2 a2[8];
            pow_chain16_pk(__expf(dv * An0), a2);
            float4 B0 = sB4[t][0], B1 = sB4[t][1], B2 = sB4[t][2], B3 = sB4[t][3];
            float4 C0 = sC4[t][0], C1 = sC4[t][1], C2 = sC4[t][2], C3 = sC4[t][3];
            f32x2 y2 = (f32x2)(0.f);
            h2[0] = h2[0] * a2[0] + dx * (f32x2){B0.x, B0.y};  y2 = y2 + h2[0] * (f32x2){C0.x, C0.y};
            h2[1] = h2[1] * a2[1] + dx * (f32x2){B0.z, B0.w};  y2 = y2 + h2[1] * (f32x2){C0.z, C0.w};
            h2[2] = h2[2] * a2[2] + dx * (f32x2){B1.x, B1.y};  y2 = y2 + h2[2] * (f32x2){C1.x, C1.y};
            h2[3] = h2[3] * a2[3] + dx * (f32x2){B1.z, B1.w};  y2 = y2 + h2[3] * (f32x2){C1.z, C1.w};
            h2[4] = h2[4] * a2[4] + dx * (f32x2){B2.x, B2.y};  y2 = y2 + h2[4] * (f32x2){C2.x, C2.y};
            h2[5] = h2[5] * a2[5] + dx * (f32x2){B2.z, B2.w};  y2 = y2 + h2[5] * (f32x2){C2.z, C2.w};
            h2[6] = h2[6] * a2[6] + dx * (f32x2){B3.x, B3.y};  y2 = y2 + h2[6] * (f32x2){C3.x, C3.y};
            h2[7] = h2[7] * a2[7] + dx * (f32x2){B3.z, B3.w};  y2 = y2 + h2[7] * (f32x2){C3.z, C3.w};
            float y = y2.x + y2.y + xv * Dv;
            y *= zv;
            yl[t][d] = to_bf16(y);
        }
    } else {
        #pragma unroll 4
        for (int t = 0; t < CHUNK; ++t) {
            unsigned pw = pwv[t];
            float dv = bf2f((unsigned short)(pw & 0xffffu));
            float xv = bf2f((unsigned short)(pw >> 16));
            float zv = bf2f(zs[(size_t)(rbase + t) * 512 + d]);
            float dx = dv * xv;
            float4 B0 = sB4[t][0], B1 = sB4[t][1], B2 = sB4[t][2], B3 = sB4[t][3];
            float4 C0 = sC4[t][0], C1 = sC4[t][1], C2 = sC4[t][2], C3 = sC4[t][3];
            f32x2 e0 = { __expf(dv * An[0]),  __expf(dv * An[1])  };
            f32x2 e1 = { __expf(dv * An[2]),  __expf(dv * An[3])  };
            f32x2 e2 = { __expf(dv * An[4]),  __expf(dv * An[5])  };
            f32x2 e3 = { __expf(dv * An[6]),  __expf(dv * An[7])  };
            f32x2 e4 = { __expf(dv * An[8]),  __expf(dv * An[9])  };
            f32x2 e5 = { __expf(dv * An[10]), __expf(dv * An[11]) };
            f32x2 e6 = { __expf(dv * An[12]), __expf(dv * An[13]) };
            f32x2 e7 = { __expf(dv * An[14]), __expf(dv * An[15]) };
            f32x2 y2 = (f32x2)(0.f);
            h2[0] = h2[0] * e0 + dx * (f32x2){B0.x, B0.y};  y2 = y2 + h2[0] * (f32x2){C0.x, C0.y};
            h2[1] = h2[1] * e1 + dx * (f32x2){B0.z, B0.w};  y2 = y2 + h2[1] * (f32x2){C0.z, C0.w};
            h2[2] = h2[2] * e2 + dx * (f32x2){B1.x, B1.y};  y2 = y2 + h2[2] * (f32x2){C1.x, C1.y};
            h2[3] = h2[3] * e3 + dx * (f32x2){B1.z, B1.w};  y2 = y2 + h2[3] * (f32x2){C1.z, C1.w};
            h2[4] = h2[4] * e4 + dx * (f32x2){B2.x, B2.y};  y2 = y2 + h2[4] * (f32x2){C2.x, C2.y};
            h2[5] = h2[5] * e5 + dx * (f32x2){B2.z, B2.w};  y2 = y2 + h2[5] * (f32x2){C2.z, C2.w};
            h2[6] = h2[6] * e6 + dx * (f32x2){B3.x, B3.y};  y2 = y2 + h2[6] * (f32x2){C3.x, C3.y};
            h2[7] = h2[7] * e7 + dx * (f32x2){B3.z, B3.w};  y2 = y2 + h2[7] * (f32x2){C3.z, C3.w};
            float y = y2.x + y2.y + xv * Dv;
            y *= zv;
            yl[t][d] = to_bf16(y);
        }
    }
    __syncthreads();

    // ---- out GEMM: [32 t x 128 c] = yl[32x512] @ WcT[128x512]^T ----
    {
        int wv = tid >> 6, ln = tid & 63;       // wave wv owns c-tile wv
        int fm = ln & 15, fk = (ln >> 4) * 8;
        f32x4 acc0 = (f32x4)(0.f), acc1 = (f32x4)(0.f);
        const unsigned short* wrow = &WcT[(size_t)(wv * 16 + fm) * 512];
        #pragma unroll 4
        for (int k0 = 0; k0 < 512; k0 += 32) {
            bf16x8 af = *(const bf16x8*)&wrow[k0 + fk];
            bf16x8 b0 = *(const bf16x8*)&yl[fm][k0 + fk];
            bf16x8 b1 = *(const bf16x8*)&yl[16 + fm][k0 + fk];
            acc0 = __builtin_amdgcn_mfma_f32_16x16x32_bf16(af, b0, acc0, 0, 0, 0);
            acc1 = __builtin_amdgcn_mfma_f32_16x16x32_bf16(af, b1, acc1, 0, 0, 0);
        }
        int ccol = ln & 15, crow = (ln >> 4) * 4;
        #pragma unroll
        for (int r = 0; r < 4; ++r) {
            int c = wv * 16 + crow + r;
            float bias = bo[c];
            size_t obase = ((size_t)(b * 128 + c)) * LSEQ + chunk * CHUNK;
            out[obase + ccol]      = acc0[r] + bias;
            out[obase + 16 + ccol] = acc1[r] + bias;
        }
    }
}

// ---------------- launch ----------------
extern "C" void kernel_launch(void* const* d_in, const int* in_sizes, int n_in,
                              void* d_out, int out_size, void* d_ws, size_t ws_size,
                              hipStream_t stream) {
    (void)in_sizes; (void)n_in; (void)out_size; (void)ws_size;
    const float* input    = (const float*)d_in[0];
    const float* input2   = (const float*)d_in[1];
    const float* ln_g     = (const float*)d_in[2];
    const float* ln_b     = (const float*)d_in[3];
    const float* outp_w   = (const float*)d_in[4];
    const float* outp_b   = (const float*)d_in[5];
    const float* in_proj  = (const float*)d_in[6];
    const float* conv_w   = (const float*)d_in[7];
    const float* conv_b   = (const float*)d_in[8];
    const float* x_proj   = (const float*)d_in[9];
    const float* dt_w     = (const float*)d_in[10];
    const float* dt_b     = (const float*)d_in[11];
    const float* A_log    = (const float*)d_in[12];
    const float* D_param  = (const float*)d_in[13];
    const float* mout_w   = (const float*)d_in[14];
    float* out = (float*)d_out;

    char* ws = (char*)d_ws;
    unsigned short* xh    = (unsigned short*)ws;                    ws += (size_t)NR * 512 * 2;
    unsigned short* zsbuf = (unsigned short*)ws;                    ws += (size_t)NR * 512 * 2;
    unsigned*       dxp   = (unsigned*)ws;                          ws += (size_t)NR * 512 * 4;
    unsigned short* Abf   = (unsigned short*)ws;                    ws += (size_t)NR * 256 * 2;
    unsigned short* Wt    = (unsigned short*)ws;                    ws += (size_t)1024 * 256 * 2;
    unsigned short* WcT   = (unsigned short*)ws;                    ws += (size_t)128 * 512 * 2;
    unsigned short* Wxpt  = (unsigned short*)ws;                    ws += (size_t)48 * 512 * 2;
    float* anegp = (float*)ws;                                      ws += (size_t)512 * 16 * 4;
    float* xdbl = (float*)ws;                                       ws += (size_t)NR * 32 * 4;
    float* Sarr = (float*)ws;                                       ws += (size_t)NCH * 2048 * 4;
    float* Harr = (float*)ws;                                       ws += (size_t)NCH * 32768 * 4;

    front_kernel<<<960, 256, 0, stream>>>(input, input2, ln_g, ln_b, mout_w, outp_w,
                                          x_proj, A_log, in_proj,
                                          Abf, WcT, Wxpt, anegp, Wt);
    gemm1_mfma<<<dim3(128, 8), 256, 0, stream>>>(Abf, Wt, xh, zsbuf);
    mid_kernel<<<NB * NCH, 512, 0, stream>>>(xh, conv_w, conv_b, Wxpt, dt_w, dt_b,
                                             anegp, dxp, xdbl, Sarr, Harr);
    scan_pass2<<<256, 128, 0, stream>>>(Sarr, anegp, Harr);
    scan_pass3_out<<<NB * NCH, 512, 0, stream>>>(dxp, zsbuf, xdbl, anegp, D_param,
                                                 Harr, WcT, outp_b, out);
}

// Round 14
// 192.630 us; speedup vs baseline: 1.0481x; 1.0155x over previous
//
#include <hip/hip_runtime.h>
#include <hip/hip_bf16.h>
#include <math.h>

#define LSEQ 4096
#define NR   16384   // B*L
#define NB   4
#define CHUNK 32
#define NCH  128

typedef short bf16x8 __attribute__((ext_vector_type(8)));
typedef float f32x4  __attribute__((ext_vector_type(4)));
typedef float f32x2  __attribute__((ext_vector_type(2)));

typedef __attribute__((address_space(1))) const void gvoid_t;
typedef __attribute__((address_space(3))) void svoid_t;

__device__ __forceinline__ void gld_lds16(void* lds, const void* g) {
    __builtin_amdgcn_global_load_lds((gvoid_t*)g, (svoid_t*)lds, 16, 0, 0);
}

__device__ __forceinline__ unsigned short to_bf16(float f) {
    union { float f; unsigned u; } x; x.f = f;
    unsigned r = (x.u + 0x7fff + ((x.u >> 16) & 1)) >> 16;
    return (unsigned short)r;
}
__device__ __forceinline__ float bf2f(unsigned short u) {
    union { unsigned u; float f; } x; x.u = ((unsigned)u) << 16;
    return x.f;
}
__device__ __forceinline__ float softplus_f(float x) {
    return x > 20.f ? x : __logf(1.f + __expf(x));
}
__device__ __forceinline__ float silu_f(float x) {
    return x / (1.f + __expf(-x));
}

// packed pow chain: a2[i] = {r^(2i+1), r^(2i+2)} — bit-identical mult trees to scalar version
__device__ __forceinline__ void pow_chain16_pk(float r, f32x2* a2) {
    float r2 = r * r;
    float r4 = r2 * r2;
    float r8 = r4 * r4;
    f32x2 v01 = { r, r2 };
    a2[0] = v01;
    a2[1] = v01 * r2;    // r3,  r4
    a2[2] = v01 * r4;    // r5,  r6
    a2[3] = a2[1] * r4;  // r7,  r8
    a2[4] = v01 * r8;    // r9,  r10
    a2[5] = a2[1] * r8;  // r11, r12
    a2[6] = a2[2] * r8;  // r13, r14
    a2[7] = a2[3] * r8;  // r15, r16
}

// per-thread check: An[n] == (n+1) * An[0] for all n (power-structure of A)
__device__ __forceinline__ bool pow_ok16(const float* An) {
    bool ok = true;
    #pragma unroll
    for (int n = 1; n < 16; ++n) {
        float ref = (float)(n + 1) * An[0];
        ok = ok && (fabsf(An[n] - ref) <= 1e-4f * fabsf(An[n]) + 1e-30f);
    }
    return ok;
}

// ---------------- K1: merged front (ln | wct | wxpt | aneg | Wt-transpose) ----------------
__global__ __launch_bounds__(256) void front_kernel(const float* __restrict__ in1,
                                                    const float* __restrict__ in2,
                                                    const float* __restrict__ g,
                                                    const float* __restrict__ beta,
                                                    const float* __restrict__ Wm,
                                                    const float* __restrict__ Wo,
                                                    const float* __restrict__ Wxp,
                                                    const float* __restrict__ A_log,
                                                    const float* __restrict__ W,
                                                    unsigned short* __restrict__ Abf,
                                                    unsigned short* __restrict__ WcT,
                                                    unsigned short* __restrict__ Wxpt,
                                                    float* __restrict__ anegp,
                                                    unsigned short* __restrict__ Wt) {
    __shared__ float tile[256][33];   // 8448 floats; transpose branch uses flat 64*65=4160
    int blk = blockIdx.x;
    int tid = threadIdx.x;
    if (blk < 512) {
        // ---- layernorm + transpose + bf16 ----
        __shared__ float s1[8][32], s2[8][32];
        __shared__ float smu[32], srs[32];
        int b  = blk >> 7;
        int t0 = (blk & 127) * 32;
        #pragma unroll
        for (int p = 0; p < 8; ++p) {
            int c = p * 32 + (tid >> 3);
            int toff = (tid & 7) * 4;
            const float* src = (c < 128) ? &in1[((size_t)(b * 128 + c)) * LSEQ + t0 + toff]
                                         : &in2[((size_t)(b * 128 + (c - 128))) * LSEQ + t0 + toff];
            float4 v = *(const float4*)src;
            tile[c][toff] = v.x; tile[c][toff+1] = v.y;
            tile[c][toff+2] = v.z; tile[c][toff+3] = v.w;
        }
        __syncthreads();
        {
            int t = tid & 31, gg = tid >> 5;
            float a1 = 0.f, a2 = 0.f;
            #pragma unroll
            for (int i = 0; i < 32; ++i) {
                float v = tile[gg * 32 + i][t];
                a1 += v; a2 += v * v;
            }
            s1[gg][t] = a1; s2[gg][t] = a2;
        }
        __syncthreads();
        if (tid < 32) {
            float a1 = 0.f, a2 = 0.f;
            #pragma unroll
            for (int gg = 0; gg < 8; ++gg) { a1 += s1[gg][tid]; a2 += s2[gg][tid]; }
            float m = a1 * (1.f / 256.f);
            float var = a2 * (1.f / 256.f) - m * m;
            smu[tid] = m;
            srs[tid] = rsqrtf(var + 1e-5f);
        }
        __syncthreads();
        int c = tid;
        float gc = g[c], bc = beta[c];
        #pragma unroll 4
        for (int t = 0; t < 32; ++t) {
            float v = (tile[c][t] - smu[t]) * srs[t] * gc + bc;
            Abf[((size_t)((b << 12) + t0 + t)) * 256 + c] = to_bf16(v);
        }
    } else if (blk < 768) {
        int gid = (blk - 512) * 256 + tid;    // 65536
        int row = gid >> 7, col = gid & 127;
        float acc = 0.f;
        #pragma unroll 8
        for (int k = 0; k < 256; ++k) acc += Wm[row * 256 + k] * Wo[k * 128 + col];
        WcT[(size_t)col * 512 + row] = to_bf16(acc);
    } else if (blk < 864) {
        int gid = (blk - 768) * 256 + tid;    // 24576
        int n = gid >> 9, k = gid & 511;
        Wxpt[gid] = to_bf16(Wxp[(size_t)k * 48 + n]);
    } else if (blk < 896) {
        int gid = (blk - 864) * 256 + tid;    // 8192
        anegp[gid] = -__expf(A_log[gid]);
    } else {
        // ---- Wt transpose: flat view with stride 65 (bank-conflict-free) ----
        float* tf = &tile[0][0];
        int local = blk - 896;                // 0..63
        int k0 = (local & 3) * 64;
        int n0 = (local >> 2) * 64;
        int a = tid & 63, q = tid >> 6;
        #pragma unroll
        for (int i = 0; i < 16; ++i) {
            int k = q * 16 + i;
            tf[k * 65 + a] = W[(size_t)(k0 + k) * 1024 + n0 + a];
        }
        __syncthreads();
        #pragma unroll
        for (int i = 0; i < 16; ++i) {
            int n = q * 16 + i;
            Wt[(size_t)(n0 + n) * 256 + k0 + a] = to_bf16(tf[a * 65 + n]);
        }
    }
}

// ---------------- K2: MFMA in_proj GEMM, silu on z half, bf16 out ----------------
// launch_bounds(256,4): min 4 waves/EU -> VGPR capped at 128, 4 blocks/CU capacity.
__global__ __launch_bounds__(256, 4) void gemm1_mfma(const unsigned short* __restrict__ Abf,
                                                     const unsigned short* __restrict__ Wt,
                                                     unsigned short* __restrict__ xh,
                                                     unsigned short* __restrict__ zs) {
    __shared__ __align__(16) short Asl[128][32];
    __shared__ __align__(16) short Bsl[128][32];
    int tid = threadIdx.x;
    int wv = tid >> 6, ln = tid & 63;
    int m0 = blockIdx.x * 128;
    int n0 = blockIdx.y * 128;
    int mw = (wv & 1) * 64, nw = (wv >> 1) * 64;

    f32x4 acc[4][4];
    #pragma unroll
    for (int i = 0; i < 4; ++i)
        #pragma unroll
        for (int j = 0; j < 4; ++j) acc[i][j] = (f32x4)(0.f);

    int srow  = ln >> 2;
    int skoff = (ln & 3) * 8;

    for (int k0 = 0; k0 < 256; k0 += 32) {
        #pragma unroll
        for (int i = 0; i < 2; ++i) {
            int j = wv * 2 + i;
            int row = j * 16 + srow;
            gld_lds16(&Asl[j * 16][0], &Abf[(size_t)(m0 + row) * 256 + k0 + skoff]);
            gld_lds16(&Bsl[j * 16][0], &Wt [(size_t)(n0 + row) * 256 + k0 + skoff]);
        }
        __syncthreads();
        bf16x8 af[4], bff[4];
        int fm = ln & 15, fk = (ln >> 4) * 8;
        #pragma unroll
        for (int i = 0; i < 4; ++i) {
            af[i]  = *(const bf16x8*)&Asl[mw + i * 16 + fm][fk];
            bff[i] = *(const bf16x8*)&Bsl[nw + i * 16 + fm][fk];
        }
        #pragma unroll
        for (int i = 0; i < 4; ++i)
            #pragma unroll
            for (int j = 0; j < 4; ++j)
                acc[i][j] = __builtin_amdgcn_mfma_f32_16x16x32_bf16(af[i], bff[j], acc[i][j], 0, 0, 0);
        __syncthreads();
    }
    int ccol = ln & 15, crow = (ln >> 4) * 4;
    bool zhalf = (n0 >= 512);
    #pragma unroll
    for (int i = 0; i < 4; ++i) {
        #pragma unroll
        for (int j = 0; j < 4; ++j) {
            int n = n0 + nw + j * 16 + ccol;
            #pragma unroll
            for (int r = 0; r < 4; ++r) {
                int m = m0 + mw + i * 16 + crow + r;
                float v = acc[i][j][r];
                if (zhalf) zs[(size_t)m * 512 + (n - 512)] = to_bf16(silu_f(v));
                else       xh[(size_t)m * 512 + n]         = to_bf16(v);
            }
        }
    }
}

// ---------------- K3 (fused): conv + xproj-MFMA + dt/pack + scan pass 1 ----------------
// one block = one (b, chunk): 512 threads, thread d owns channel d.
// LDS reads via ds_read_b128 (float4), pairs extracted in-register — bit-identical math.
__global__ __launch_bounds__(512, 4) void mid_kernel(const unsigned short* __restrict__ xh,
                                                     const float* __restrict__ cw,
                                                     const float* __restrict__ cb,
                                                     const unsigned short* __restrict__ Wxpt,
                                                     const float* __restrict__ Wdt,
                                                     const float* __restrict__ dtb,
                                                     const float* __restrict__ anegp,
                                                     unsigned* __restrict__ dxp,
                                                     float* __restrict__ xdbl,
                                                     float* __restrict__ Sarr,
                                                     float* __restrict__ Harr) {
    __shared__ __align__(16) unsigned short xcs[CHUNK][520];
    __shared__ __align__(16) float xds[CHUNK][48];
    int tid = threadIdx.x;              // 0..511 == d
    int chunk = blockIdx.x & (NCH - 1);
    int b     = blockIdx.x >> 7;
    int d = tid;
    int rbase = (b << 12) + chunk * CHUNK;

    // early per-thread parameter loads (hide latency under conv)
    float4 w4 = *(const float4*)&cw[d * 4];
    float cbd = cb[d];
    float An[16];
    #pragma unroll
    for (int n = 0; n < 16; n += 4) {
        float4 v = *(const float4*)&anegp[d * 16 + n];
        An[n] = v.x; An[n+1] = v.y; An[n+2] = v.z; An[n+3] = v.w;
    }
    f32x2 wdt2[8];
    #pragma unroll
    for (int q = 0; q < 8; ++q) {
        wdt2[q].x = Wdt[(2 * q) * 512 + d];
        wdt2[q].y = Wdt[(2 * q + 1) * 512 + d];
    }
    float bd = dtb[d];

    // ---- conv k=4 + silu, sliding window over 35 rows of xh ----
    float x0 = 0.f, x1 = 0.f, x2 = 0.f;
    if (chunk > 0) {   // chunks never cross a batch; chunk==0 -> zero left halo
        x0 = bf2f(xh[(size_t)(rbase - 3) * 512 + d]);
        x1 = bf2f(xh[(size_t)(rbase - 2) * 512 + d]);
        x2 = bf2f(xh[(size_t)(rbase - 1) * 512 + d]);
    }
    #pragma unroll
    for (int t = 0; t < CHUNK; ++t) {
        float x3 = bf2f(xh[(size_t)(rbase + t) * 512 + d]);
        float a = x0 * w4.x + x1 * w4.y + x2 * w4.z + x3 * w4.w + cbd;
        xcs[t][d] = to_bf16(silu_f(a));
        x0 = x1; x1 = x2; x2 = x3;
    }
    __syncthreads();

    // ---- xproj MFMA: waves 0..5 each own one 16x16 tile of xds[32][48] ----
    {
        int wv = tid >> 6, ln = tid & 63;
        if (wv < 6) {
            int mt = (wv >= 3) ? 16 : 0;
            int wr = (wv >= 3) ? wv - 3 : wv;
            int nt = wr * 16;
            int fm = ln & 15, fk = (ln >> 4) * 8;
            f32x4 acc = (f32x4)(0.f);
            #pragma unroll 4
            for (int k0 = 0; k0 < 512; k0 += 32) {
                bf16x8 af  = *(const bf16x8*)&xcs[mt + fm][k0 + fk];
                bf16x8 bf_ = *(const bf16x8*)&Wxpt[(size_t)(nt + fm) * 512 + k0 + fk];
                acc = __builtin_amdgcn_mfma_f32_16x16x32_bf16(af, bf_, acc, 0, 0, 0);
            }
            int ccol = ln & 15, crow = (ln >> 4) * 4;
            #pragma unroll
            for (int r = 0; r < 4; ++r)
                xds[mt + crow + r][nt + ccol] = acc[r];
        }
    }
    __syncthreads();

    // ---- write B,C (cols 16..48) to global xdbl[NR][32] for pass3 ----
    #pragma unroll
    for (int i = 0; i < 2; ++i) {
        int idx = tid + i * 512;          // 0..1023 = t*32+n, fully coalesced
        int t = idx >> 5, n = idx & 31;
        xdbl[(size_t)(rbase + t) * 32 + n] = xds[t][16 + n];
    }

    // ---- dt + softplus + pack + in-register chunk scan (pass 1), b128 LDS reads ----
    bool pm = pow_ok16(An);
    f32x2 h2[8];
    #pragma unroll
    for (int n = 0; n < 8; ++n) h2[n] = (f32x2)(0.f);
    float S = 0.f;
    const float4* xds4 = (const float4*)&xds[0][0];   // [32][12]
    if (pm) {
        float An0 = An[0];
        #pragma unroll 4
        for (int t = 0; t < CHUNK; ++t) {
            float4 q0 = xds4[t * 12 + 0], q1 = xds4[t * 12 + 1];
            float4 q2 = xds4[t * 12 + 2], q3 = xds4[t * 12 + 3];
            f32x2 acc2 = { bd, 0.f };
            acc2 = acc2 + (f32x2){q0.x, q0.y} * wdt2[0];
            acc2 = acc2 + (f32x2){q0.z, q0.w} * wdt2[1];
            acc2 = acc2 + (f32x2){q1.x, q1.y} * wdt2[2];
            acc2 = acc2 + (f32x2){q1.z, q1.w} * wdt2[3];
            acc2 = acc2 + (f32x2){q2.x, q2.y} * wdt2[4];
            acc2 = acc2 + (f32x2){q2.z, q2.w} * wdt2[5];
            acc2 = acc2 + (f32x2){q3.x, q3.y} * wdt2[6];
            acc2 = acc2 + (f32x2){q3.z, q3.w} * wdt2[7];
            float a = acc2.x + acc2.y;
            unsigned short dbf = to_bf16(softplus_f(a));
            unsigned short xbf = xcs[t][d];
            float dv = bf2f(dbf), xv = bf2f(xbf);
            dxp[(size_t)(rbase + t) * 512 + d] = (unsigned)dbf | ((unsigned)xbf << 16);
            float dx = dv * xv;
            S += dv;
            f32x2 a2[8];
            pow_chain16_pk(__expf(dv * An0), a2);
            float4 B0 = xds4[t * 12 + 4], B1 = xds4[t * 12 + 5];
            float4 B2 = xds4[t * 12 + 6], B3 = xds4[t * 12 + 7];
            h2[0] = h2[0] * a2[0] + dx * (f32x2){B0.x, B0.y};
            h2[1] = h2[1] * a2[1] + dx * (f32x2){B0.z, B0.w};
            h2[2] = h2[2] * a2[2] + dx * (f32x2){B1.x, B1.y};
            h2[3] = h2[3] * a2[3] + dx * (f32x2){B1.z, B1.w};
            h2[4] = h2[4] * a2[4] + dx * (f32x2){B2.x, B2.y};
            h2[5] = h2[5] * a2[5] + dx * (f32x2){B2.z, B2.w};
            h2[6] = h2[6] * a2[6] + dx * (f32x2){B3.x, B3.y};
            h2[7] = h2[7] * a2[7] + dx * (f32x2){B3.z, B3.w};
        }
    } else {
        #pragma unroll 2
        for (int t = 0; t < CHUNK; ++t) {
            float4 q0 = xds4[t * 12 + 0], q1 = xds4[t * 12 + 1];
            float4 q2 = xds4[t * 12 + 2], q3 = xds4[t * 12 + 3];
            f32x2 acc2 = { bd, 0.f };
            acc2 = acc2 + (f32x2){q0.x, q0.y} * wdt2[0];
            acc2 = acc2 + (f32x2){q0.z, q0.w} * wdt2[1];
            acc2 = acc2 + (f32x2){q1.x, q1.y} * wdt2[2];
            acc2 = acc2 + (f32x2){q1.z, q1.w} * wdt2[3];
            acc2 = acc2 + (f32x2){q2.x, q2.y} * wdt2[4];
            acc2 = acc2 + (f32x2){q2.z, q2.w} * wdt2[5];
            acc2 = acc2 + (f32x2){q3.x, q3.y} * wdt2[6];
            acc2 = acc2 + (f32x2){q3.z, q3.w} * wdt2[7];
            float a = acc2.x + acc2.y;
            unsigned short dbf = to_bf16(softplus_f(a));
            unsigned short xbf = xcs[t][d];
            float dv = bf2f(dbf), xv = bf2f(xbf);
            dxp[(size_t)(rbase + t) * 512 + d] = (unsigned)dbf | ((unsigned)xbf << 16);
            float dx = dv * xv;
            S += dv;
            float4 B0 = xds4[t * 12 + 4], B1 = xds4[t * 12 + 5];
            float4 B2 = xds4[t * 12 + 6], B3 = xds4[t * 12 + 7];
            f32x2 e0 = { __expf(dv * An[0]),  __expf(dv * An[1])  };
            f32x2 e1 = { __expf(dv * An[2]),  __expf(dv * An[3])  };
            f32x2 e2 = { __expf(dv * An[4]),  __expf(dv * An[5])  };
            f32x2 e3 = { __expf(dv * An[6]),  __expf(dv * An[7])  };
            f32x2 e4 = { __expf(dv * An[8]),  __expf(dv * An[9])  };
            f32x2 e5 = { __expf(dv * An[10]), __expf(dv * An[11]) };
            f32x2 e6 = { __expf(dv * An[12]), __expf(dv * An[13]) };
            f32x2 e7 = { __expf(dv * An[14]), __expf(dv * An[15]) };
            h2[0] = h2[0] * e0 + dx * (f32x2){B0.x, B0.y};
            h2[1] = h2[1] * e1 + dx * (f32x2){B0.z, B0.w};
            h2[2] = h2[2] * e2 + dx * (f32x2){B1.x, B1.y};
            h2[3] = h2[3] * e3 + dx * (f32x2){B1.z, B1.w};
            h2[4] = h2[4] * e4 + dx * (f32x2){B2.x, B2.y};
            h2[5] = h2[5] * e5 + dx * (f32x2){B2.z, B2.w};
            h2[6] = h2[6] * e6 + dx * (f32x2){B3.x, B3.y};
            h2[7] = h2[7] * e7 + dx * (f32x2){B3.z, B3.w};
        }
    }
    Sarr[(size_t)chunk * 2048 + b * 512 + d] = S;
    size_t gbase = ((size_t)(b * 512 + d)) * 16;
    size_t coff  = (size_t)chunk * 32768;
    #pragma unroll
    for (int n = 0; n < 4; ++n) {
        *(float4*)&Harr[coff + gbase + n * 4] =
            make_float4(h2[2*n].x, h2[2*n].y, h2[2*n+1].x, h2[2*n+1].y);
    }
}

// ---------------- K4: scan pass 2 (carry across chunks; P = exp(S*An)) ----------------
// 256 blocks x 128 threads: all 256 CUs active.
__global__ __launch_bounds__(128) void scan_pass2(const float* __restrict__ Sarr,
                                                  const float* __restrict__ anegp,
                                                  float* __restrict__ Harr) {
    int gid = blockIdx.x * 128 + threadIdx.x;   // 32768 = b*8192 + d*16 + n
    float An = anegp[gid & 8191];
    int sidx = gid >> 4;                        // b*512 + d
    float carry = 0.f;
    #pragma unroll 8
    for (int c = 0; c < NCH; ++c) {
        float S  = Sarr[(size_t)c * 2048 + sidx];
        size_t off = (size_t)c * 32768 + gid;
        float he = Harr[off];
        Harr[off] = carry;
        carry = he + __expf(S * An) * carry;
    }
}

// ---------------- K5 (fused): scan pass 3 + out GEMM ----------------
// one block = one (b, chunk): 512 threads, thread d owns channel d.
// B/C read DIRECTLY from global xdbl with wave-uniform addresses (scalarizable ->
// SMEM pipe, off the LDS pipe). No sB4/sC4 staging, no staging barrier. Bit-exact.
__global__ __launch_bounds__(512, 4) void scan_pass3_out(const unsigned* __restrict__ dxp,
                                                         const unsigned short* __restrict__ zs,
                                                         const float* __restrict__ xdbl,
                                                         const float* __restrict__ anegp,
                                                         const float* __restrict__ Dp,
                                                         const float* __restrict__ Hin,
                                                         const unsigned short* __restrict__ WcT,
                                                         const float* __restrict__ bo,
                                                         float* __restrict__ out) {
    __shared__ __align__(16) unsigned short yl[CHUNK][520];
    int tid = threadIdx.x;
    int chunk = blockIdx.x & (NCH - 1);
    int b     = blockIdx.x >> 7;
    int d = tid;
    int rbase = (b << 12) + chunk * CHUNK;
    unsigned pwv[CHUNK];
    #pragma unroll
    for (int t = 0; t < CHUNK; ++t)
        pwv[t] = dxp[(size_t)(rbase + t) * 512 + d];
    float An[16];
    #pragma unroll
    for (int n = 0; n < 16; n += 4) {
        float4 v = *(const float4*)&anegp[d * 16 + n];
        An[n] = v.x; An[n+1] = v.y; An[n+2] = v.z; An[n+3] = v.w;
    }
    bool pm = pow_ok16(An);
    float Dv = Dp[d];
    size_t gbase = ((size_t)(b * 512 + d)) * 16;
    size_t coff  = (size_t)chunk * 32768;
    f32x2 h2[8];
    #pragma unroll
    for (int n = 0; n < 4; ++n) {
        float4 v = *(const float4*)&Hin[coff + gbase + n * 4];
        h2[2*n].x = v.x; h2[2*n].y = v.y; h2[2*n+1].x = v.z; h2[2*n+1].y = v.w;
    }
    if (pm) {
        float An0 = An[0];
        #pragma unroll 8
        for (int t = 0; t < CHUNK; ++t) {
            unsigned pw = pwv[t];
            float dv = bf2f((unsigned short)(pw & 0xffffu));
            float xv = bf2f((unsigned short)(pw >> 16));
            float zv = bf2f(zs[(size_t)(rbase + t) * 512 + d]);
            float dx = dv * xv;
            f32x2 a2[8];
            pow_chain16_pk(__expf(dv * An0), a2);
            const float4* xrow = (const float4*)&xdbl[(size_t)(rbase + t) * 32];
            float4 B0 = xrow[0], B1 = xrow[1], B2 = xrow[2], B3 = xrow[3];
            float4 C0 = xrow[4], C1 = xrow[5], C2 = xrow[6], C3 = xrow[7];
            f32x2 y2 = (f32x2)(0.f);
            h2[0] = h2[0] * a2[0] + dx * (f32x2){B0.x, B0.y};  y2 = y2 + h2[0] * (f32x2){C0.x, C0.y};
            h2[1] = h2[1] * a2[1] + dx * (f32x2){B0.z, B0.w};  y2 = y2 + h2[1] * (f32x2){C0.z, C0.w};
            h2[2] = h2[2] * a2[2] + dx * (f32x2){B1.x, B1.y};  y2 = y2 + h2[2] * (f32x2){C1.x, C1.y};
            h2[3] = h2[3] * a2[3] + dx * (f32x2){B1.z, B1.w};  y2 = y2 + h2[3] * (f32x2){C1.z, C1.w};
            h2[4] = h2[4] * a2[4] + dx * (f32x2){B2.x, B2.y};  y2 = y2 + h2[4] * (f32x2){C2.x, C2.y};
            h2[5] = h2[5] * a2[5] + dx * (f32x2){B2.z, B2.w};  y2 = y2 + h2[5] * (f32x2){C2.z, C2.w};
            h2[6] = h2[6] * a2[6] + dx * (f32x2){B3.x, B3.y};  y2 = y2 + h2[6] * (f32x2){C3.x, C3.y};
            h2[7] = h2[7] * a2[7] + dx * (f32x2){B3.z, B3.w};  y2 = y2 + h2[7] * (f32x2){C3.z, C3.w};
            float y = y2.x + y2.y + xv * Dv;
            y *= zv;
            yl[t][d] = to_bf16(y);
        }
    } else {
        #pragma unroll 4
        for (int t = 0; t < CHUNK; ++t) {
            unsigned pw = pwv[t];
            float dv = bf2f((unsigned short)(pw & 0xffffu));
            float xv = bf2f((unsigned short)(pw >> 16));
            float zv = bf2f(zs[(size_t)(rbase + t) * 512 + d]);
            float dx = dv * xv;
            const float4* xrow = (const float4*)&xdbl[(size_t)(rbase + t) * 32];
            float4 B0 = xrow[0], B1 = xrow[1], B2 = xrow[2], B3 = xrow[3];
            float4 C0 = xrow[4], C1 = xrow[5], C2 = xrow[6], C3 = xrow[7];
            f32x2 e0 = { __expf(dv * An[0]),  __expf(dv * An[1])  };
            f32x2 e1 = { __expf(dv * An[2]),  __expf(dv * An[3])  };
            f32x2 e2 = { __expf(dv * An[4]),  __expf(dv * An[5])  };
            f32x2 e3 = { __expf(dv * An[6]),  __expf(dv * An[7])  };
            f32x2 e4 = { __expf(dv * An[8]),  __expf(dv * An[9])  };
            f32x2 e5 = { __expf(dv * An[10]), __expf(dv * An[11]) };
            f32x2 e6 = { __expf(dv * An[12]), __expf(dv * An[13]) };
            f32x2 e7 = { __expf(dv * An[14]), __expf(dv * An[15]) };
            f32x2 y2 = (f32x2)(0.f);
            h2[0] = h2[0] * e0 + dx * (f32x2){B0.x, B0.y};  y2 = y2 + h2[0] * (f32x2){C0.x, C0.y};
            h2[1] = h2[1] * e1 + dx * (f32x2){B0.z, B0.w};  y2 = y2 + h2[1] * (f32x2){C0.z, C0.w};
            h2[2] = h2[2] * e2 + dx * (f32x2){B1.x, B1.y};  y2 = y2 + h2[2] * (f32x2){C1.x, C1.y};
            h2[3] = h2[3] * e3 + dx * (f32x2){B1.z, B1.w};  y2 = y2 + h2[3] * (f32x2){C1.z, C1.w};
            h2[4] = h2[4] * e4 + dx * (f32x2){B2.x, B2.y};  y2 = y2 + h2[4] * (f32x2){C2.x, C2.y};
            h2[5] = h2[5] * e5 + dx * (f32x2){B2.z, B2.w};  y2 = y2 + h2[5] * (f32x2){C2.z, C2.w};
            h2[6] = h2[6] * e6 + dx * (f32x2){B3.x, B3.y};  y2 = y2 + h2[6] * (f32x2){C3.x, C3.y};
            h2[7] = h2[7] * e7 + dx * (f32x2){B3.z, B3.w};  y2 = y2 + h2[7] * (f32x2){C3.z, C3.w};
            float y = y2.x + y2.y + xv * Dv;
            y *= zv;
            yl[t][d] = to_bf16(y);
        }
    }
    __syncthreads();

    // ---- out GEMM: [32 t x 128 c] = yl[32x512] @ WcT[128x512]^T ----
    {
        int wv = tid >> 6, ln = tid & 63;       // wave wv owns c-tile wv
        int fm = ln & 15, fk = (ln >> 4) * 8;
        f32x4 acc0 = (f32x4)(0.f), acc1 = (f32x4)(0.f);
        const unsigned short* wrow = &WcT[(size_t)(wv * 16 + fm) * 512];
        #pragma unroll 4
        for (int k0 = 0; k0 < 512; k0 += 32) {
            bf16x8 af = *(const bf16x8*)&wrow[k0 + fk];
            bf16x8 b0 = *(const bf16x8*)&yl[fm][k0 + fk];
            bf16x8 b1 = *(const bf16x8*)&yl[16 + fm][k0 + fk];
            acc0 = __builtin_amdgcn_mfma_f32_16x16x32_bf16(af, b0, acc0, 0, 0, 0);
            acc1 = __builtin_amdgcn_mfma_f32_16x16x32_bf16(af, b1, acc1, 0, 0, 0);
        }
        int ccol = ln & 15, crow = (ln >> 4) * 4;
        #pragma unroll
        for (int r = 0; r < 4; ++r) {
            int c = wv * 16 + crow + r;
            float bias = bo[c];
            size_t obase = ((size_t)(b * 128 + c)) * LSEQ + chunk * CHUNK;
            out[obase + ccol]      = acc0[r] + bias;
            out[obase + 16 + ccol] = acc1[r] + bias;
        }
    }
}

// ---------------- launch ----------------
extern "C" void kernel_launch(void* const* d_in, const int* in_sizes, int n_in,
                              void* d_out, int out_size, void* d_ws, size_t ws_size,
                              hipStream_t stream) {
    (void)in_sizes; (void)n_in; (void)out_size; (void)ws_size;
    const float* input    = (const float*)d_in[0];
    const float* input2   = (const float*)d_in[1];
    const float* ln_g     = (const float*)d_in[2];
    const float* ln_b     = (const float*)d_in[3];
    const float* outp_w   = (const float*)d_in[4];
    const float* outp_b   = (const float*)d_in[5];
    const float* in_proj  = (const float*)d_in[6];
    const float* conv_w   = (const float*)d_in[7];
    const float* conv_b   = (const float*)d_in[8];
    const float* x_proj   = (const float*)d_in[9];
    const float* dt_w     = (const float*)d_in[10];
    const float* dt_b     = (const float*)d_in[11];
    const float* A_log    = (const float*)d_in[12];
    const float* D_param  = (const float*)d_in[13];
    const float* mout_w   = (const float*)d_in[14];
    float* out = (float*)d_out;

    char* ws = (char*)d_ws;
    unsigned short* xh    = (unsigned short*)ws;                    ws += (size_t)NR * 512 * 2;
    unsigned short* zsbuf = (unsigned short*)ws;                    ws += (size_t)NR * 512 * 2;
    unsigned*       dxp   = (unsigned*)ws;                          ws += (size_t)NR * 512 * 4;
    unsigned short* Abf   = (unsigned short*)ws;                    ws += (size_t)NR * 256 * 2;
    unsigned short* Wt    = (unsigned short*)ws;                    ws += (size_t)1024 * 256 * 2;
    unsigned short* WcT   = (unsigned short*)ws;                    ws += (size_t)128 * 512 * 2;
    unsigned short* Wxpt  = (unsigned short*)ws;                    ws += (size_t)48 * 512 * 2;
    float* anegp = (float*)ws;                                      ws += (size_t)512 * 16 * 4;
    float* xdbl = (float*)ws;                                       ws += (size_t)NR * 32 * 4;
    float* Sarr = (float*)ws;                                       ws += (size_t)NCH * 2048 * 4;
    float* Harr = (float*)ws;                                       ws += (size_t)NCH * 32768 * 4;

    front_kernel<<<960, 256, 0, stream>>>(input, input2, ln_g, ln_b, mout_w, outp_w,
                                          x_proj, A_log, in_proj,
                                          Abf, WcT, Wxpt, anegp, Wt);
    gemm1_mfma<<<dim3(128, 8), 256, 0, stream>>>(Abf, Wt, xh, zsbuf);
    mid_kernel<<<NB * NCH, 512, 0, stream>>>(xh, conv_w, conv_b, Wxpt, dt_w, dt_b,
                                             anegp, dxp, xdbl, Sarr, Harr);
    scan_pass2<<<256, 128, 0, stream>>>(Sarr, anegp, Harr);
    scan_pass3_out<<<NB * NCH, 512, 0, stream>>>(dxp, zsbuf, xdbl, anegp, D_param,
                                                 Harr, WcT, outp_b, out);
}